// Round 1
// baseline (692.216 us; speedup 1.0000x reference)
//
#include <hip/hip_runtime.h>
#include <math.h>

#define D_   1024
#define H_   16
#define DH_  64
#define T_   1024
#define B_   2
#define P_   4
#define L_   2052      // P + 2T
#define WIN_ 256
#define MH_  4096
#define FF_  4096

typedef __attribute__((ext_vector_type(8))) short bf16x8;
typedef __attribute__((ext_vector_type(4))) float f32x4;
typedef __attribute__((ext_vector_type(8))) unsigned short ush8;

__device__ __forceinline__ unsigned short f2bf(float f) {
  unsigned int u = __builtin_bit_cast(unsigned int, f);
  u += 0x7fffu + ((u >> 16) & 1u);           // round to nearest even
  return (unsigned short)(u >> 16);
}
__device__ __forceinline__ float bf2f(unsigned short h) {
  unsigned int u = ((unsigned int)h) << 16;
  return __builtin_bit_cast(float, u);
}

// ---------------- fp32 -> bf16 conversion ----------------
__global__ void cvt_bf16_k(const float* __restrict__ in, unsigned short* __restrict__ out, int n) {
  int i = blockIdx.x * blockDim.x + threadIdx.x;
  int e = i * 4;
  if (e >= n) return;
  float4 v = *(const float4*)(in + e);
  ushort4 o;
  o.x = f2bf(v.x); o.y = f2bf(v.y); o.z = f2bf(v.z); o.w = f2bf(v.w);
  *(ushort4*)(out + e) = o;
}

// ---------------- concat: [pers | memctx | x] -> aug ----------------
__global__ void concat_k(const float* __restrict__ x, const float* __restrict__ pmem,
                         const float* __restrict__ memctx, float* __restrict__ aug) {
  int i = blockIdx.x * blockDim.x + threadIdx.x;
  if (i >= (B_ * L_ * D_) / 4) return;
  int e = i * 4;
  int d  = e % D_;
  int rl = (e / D_) % L_;
  int b  = e / (D_ * L_);
  const float* src;
  if (rl < P_)            src = pmem   + rl * D_ + d;
  else if (rl < P_ + T_)  src = memctx + ((size_t)(b * T_ + (rl - P_)) * D_ + d);
  else                    src = x      + ((size_t)(b * T_ + (rl - P_ - T_)) * D_ + d);
  *(float4*)(aug + e) = *(const float4*)(src);
}

// ---------------- layernorm (D=1024), bf16 out ----------------
__global__ __launch_bounds__(256)
void layernorm_k(const float* __restrict__ in, const float* __restrict__ g,
                 const float* __restrict__ bb, unsigned short* __restrict__ out) {
  const int row = blockIdx.x;
  const int tid = threadIdx.x;
  const float* xr = in + (size_t)row * D_;
  float4 v = *(const float4*)(xr + tid * 4);
  float s  = v.x + v.y + v.z + v.w;
  float sq = v.x * v.x + v.y * v.y + v.z * v.z + v.w * v.w;
  #pragma unroll
  for (int o = 1; o < 64; o <<= 1) { s += __shfl_xor(s, o); sq += __shfl_xor(sq, o); }
  __shared__ float red[8];
  const int wid = tid >> 6;
  if ((tid & 63) == 0) { red[wid] = s; red[4 + wid] = sq; }
  __syncthreads();
  s  = red[0] + red[1] + red[2] + red[3];
  sq = red[4] + red[5] + red[6] + red[7];
  const float mean = s * (1.0f / D_);
  const float var  = sq * (1.0f / D_) - mean * mean;
  const float inv  = rsqrtf(var + 1e-5f);
  const int c = tid * 4;
  float4 gv = *(const float4*)(g + c);
  float4 bv = *(const float4*)(bb + c);
  unsigned short* dst = out + (size_t)row * D_ + c;
  dst[0] = f2bf((v.x - mean) * inv * gv.x + bv.x);
  dst[1] = f2bf((v.y - mean) * inv * gv.y + bv.y);
  dst[2] = f2bf((v.z - mean) * inv * gv.z + bv.z);
  dst[3] = f2bf((v.w - mean) * inv * gv.w + bv.w);
}

// ---------------- bf16 MFMA GEMM: C[M,N] = epi(A[M,K] @ W[N,K]^T + bias) ----------------
// ACT: 0 none, 1 relu, 2 gelu(exact). OUTBF: bf16 vs fp32 out. RESID: add fp32 resid[M,N].
template<int ACT, int OUTBF, int RESID>
__global__ __launch_bounds__(256)
void gemm_bt_k(const unsigned short* __restrict__ A,
               const unsigned short* __restrict__ W,
               const float* __restrict__ bias,
               const float* __restrict__ resid,
               void* __restrict__ Cv,
               int M, int N, int K) {
  __shared__ unsigned short As[128][40];   // 128 x (32 + 8 pad) bf16
  __shared__ unsigned short Bs[128][40];
  const int tid  = threadIdx.x;
  const int lane = tid & 63;
  const int wid  = tid >> 6;
  const int wr   = wid >> 1, wc = wid & 1;
  const int gm0  = blockIdx.y * 128;
  const int gn0  = blockIdx.x * 128;

  const f32x4 fz = {0.f, 0.f, 0.f, 0.f};
  f32x4 acc[4][4];
  #pragma unroll
  for (int i = 0; i < 4; ++i)
    #pragma unroll
    for (int j = 0; j < 4; ++j) acc[i][j] = fz;

  const int r0 = tid >> 2;           // row 0..63
  const int kc = (tid & 3) * 8;      // 0,8,16,24
  const ush8 uz = {0, 0, 0, 0, 0, 0, 0, 0};

  for (int k0 = 0; k0 < K; k0 += 32) {
    #pragma unroll
    for (int half = 0; half < 2; ++half) {
      int row  = r0 + half * 64;
      int mrow = gm0 + row;
      ush8 av = uz;
      if (mrow < M) av = *(const ush8*)(A + (size_t)mrow * K + k0 + kc);
      *(ush8*)(&As[row][kc]) = av;
      ush8 bv = *(const ush8*)(W + (size_t)(gn0 + row) * K + k0 + kc);
      *(ush8*)(&Bs[row][kc]) = bv;
    }
    __syncthreads();
    const int fr = lane & 15;
    const int fk = (lane >> 4) * 8;
    bf16x8 af[4], bfr[4];
    #pragma unroll
    for (int i = 0; i < 4; ++i) af[i]  = *(const bf16x8*)(&As[wr * 64 + i * 16 + fr][fk]);
    #pragma unroll
    for (int j = 0; j < 4; ++j) bfr[j] = *(const bf16x8*)(&Bs[wc * 64 + j * 16 + fr][fk]);
    #pragma unroll
    for (int i = 0; i < 4; ++i)
      #pragma unroll
      for (int j = 0; j < 4; ++j)
        acc[i][j] = __builtin_amdgcn_mfma_f32_16x16x32_bf16(af[i], bfr[j], acc[i][j], 0, 0, 0);
    __syncthreads();
  }

  // epilogue: C/D layout col = lane&15, row = (lane>>4)*4 + reg
  const int fr = lane & 15;
  const int rq = (lane >> 4) * 4;
  #pragma unroll
  for (int i = 0; i < 4; ++i) {
    #pragma unroll
    for (int j = 0; j < 4; ++j) {
      const int col = gn0 + wc * 64 + j * 16 + fr;
      const float bcol = bias[col];
      #pragma unroll
      for (int r = 0; r < 4; ++r) {
        const int row = gm0 + wr * 64 + i * 16 + rq + r;
        if (row < M) {
          float v = acc[i][j][r] + bcol;
          if (RESID) v += resid[(size_t)row * N + col];
          if (ACT == 1) v = fmaxf(v, 0.f);
          if (ACT == 2) v = 0.5f * v * (1.0f + erff(v * 0.70710678f));
          if (OUTBF) ((unsigned short*)Cv)[(size_t)row * N + col] = f2bf(v);
          else       ((float*)Cv)[(size_t)row * N + col] = v;
        }
      }
    }
  }
}

// ---------------- sliding-window causal attention ----------------
// grid (ceil(L/64), H, B), block 256. 4 threads per query; K/V chunks of 64 in LDS (bf16).
__global__ __launch_bounds__(256)
void attn_k(const float* __restrict__ qkv, unsigned short* __restrict__ ctx) {
  __shared__ float          qs[64][68];   // fp32 Q tile
  __shared__ unsigned short ks[64][72];   // bf16 K chunk
  __shared__ unsigned short vs[64][72];   // bf16 V chunk
  __shared__ float          ss[64][65];   // P tile
  const int tid  = threadIdx.x;
  const int qi   = tid >> 2;
  const int part = tid & 3;
  const int qb   = blockIdx.x * 64;
  const int h    = blockIdx.y;
  const int b    = blockIdx.z;
  const int qg   = qb + qi;

  // stage Q (fp32)
  #pragma unroll
  for (int c = tid; c < 1024; c += 256) {
    int row = c >> 4, cc = (c & 15) * 4;
    int g = qb + row;
    float4 v = make_float4(0.f, 0.f, 0.f, 0.f);
    if (g < L_) v = *(const float4*)(qkv + (size_t)(b * L_ + g) * 3072 + h * 64 + cc);
    *(float4*)(&qs[row][cc]) = v;
  }

  float m = -1e30f, lsum = 0.f;
  float o_[16];
  #pragma unroll
  for (int e = 0; e < 16; ++e) o_[e] = 0.f;

  int k0 = qb - WIN_ + 1;
  if (k0 < 0) k0 = 0;
  k0 = (k0 / 64) * 64;
  __syncthreads();

  for (int kb = k0; kb <= qb + 63; kb += 64) {
    // stage K,V chunk (bf16)
    #pragma unroll
    for (int c = tid; c < 1024; c += 256) {
      int row = c >> 4, cc = (c & 15) * 4;
      int g = kb + row;
      float4 kv = make_float4(0.f, 0.f, 0.f, 0.f), vv = kv;
      if (g < L_) {
        const float* base = qkv + (size_t)(b * L_ + g) * 3072 + h * 64 + cc;
        kv = *(const float4*)(base + 1024);
        vv = *(const float4*)(base + 2048);
      }
      ushort4 k4; k4.x = f2bf(kv.x); k4.y = f2bf(kv.y); k4.z = f2bf(kv.z); k4.w = f2bf(kv.w);
      ushort4 v4; v4.x = f2bf(vv.x); v4.y = f2bf(vv.y); v4.z = f2bf(vv.z); v4.w = f2bf(vv.w);
      *(ushort4*)(&ks[row][cc]) = k4;
      *(ushort4*)(&vs[row][cc]) = v4;
    }
    __syncthreads();

    // scores: 16 keys per thread
    float sc[16];
    float cmax = -1e30f;
    #pragma unroll
    for (int jj = 0; jj < 16; ++jj) {
      const int j  = part * 16 + jj;
      const int kg = kb + j;
      float s = 0.f;
      #pragma unroll
      for (int dd = 0; dd < 64; dd += 8) {
        ush8 kv8 = *(const ush8*)(&ks[j][dd]);
        f32x4 q0 = *(const f32x4*)(&qs[qi][dd]);
        f32x4 q1 = *(const f32x4*)(&qs[qi][dd + 4]);
        s += q0[0] * bf2f(kv8[0]) + q0[1] * bf2f(kv8[1]) + q0[2] * bf2f(kv8[2]) + q0[3] * bf2f(kv8[3])
           + q1[0] * bf2f(kv8[4]) + q1[1] * bf2f(kv8[5]) + q1[2] * bf2f(kv8[6]) + q1[3] * bf2f(kv8[7]);
      }
      s *= 0.125f;
      const bool ok = (kg <= qg) && (kg + WIN_ > qg);
      sc[jj] = ok ? s : -1e30f;
      cmax = fmaxf(cmax, sc[jj]);
    }
    cmax = fmaxf(cmax, __shfl_xor(cmax, 1));
    cmax = fmaxf(cmax, __shfl_xor(cmax, 2));
    const float mnew  = fmaxf(m, cmax);
    const float scalef = __expf(m - mnew);
    float psum = 0.f;
    #pragma unroll
    for (int jj = 0; jj < 16; ++jj) {
      float p = __expf(sc[jj] - mnew);
      sc[jj] = p;
      psum += p;
    }
    psum += __shfl_xor(psum, 1);
    psum += __shfl_xor(psum, 2);
    lsum = lsum * scalef + psum;
    m = mnew;
    #pragma unroll
    for (int jj = 0; jj < 16; ++jj) ss[qi][part * 16 + jj] = sc[jj];
    #pragma unroll
    for (int e = 0; e < 16; ++e) o_[e] *= scalef;
    __syncthreads();

    // PV: each thread owns dims [part*16, part*16+16)
    #pragma unroll 4
    for (int j = 0; j < 64; ++j) {
      const float p = ss[qi][j];
      ush8 v0 = *(const ush8*)(&vs[j][part * 16]);
      ush8 v1 = *(const ush8*)(&vs[j][part * 16 + 8]);
      #pragma unroll
      for (int e = 0; e < 8; ++e) o_[e]     += p * bf2f(v0[e]);
      #pragma unroll
      for (int e = 0; e < 8; ++e) o_[8 + e] += p * bf2f(v1[e]);
    }
    __syncthreads();
  }

  if (qg < L_) {
    const float inv = 1.0f / lsum;
    unsigned short* dst = ctx + (size_t)(b * L_ + qg) * D_ + h * 64 + part * 16;
    #pragma unroll
    for (int e = 0; e < 16; ++e) dst[e] = f2bf(o_[e] * inv);
  }
}

// ---------------- launch ----------------
extern "C" void kernel_launch(void* const* d_in, const int* in_sizes, int n_in,
                              void* d_out, int out_size, void* d_ws, size_t ws_size,
                              hipStream_t stream) {
  (void)in_sizes; (void)n_in; (void)out_size; (void)ws_size;
  const float* x    = (const float*)d_in[0];
  const float* pmem = (const float*)d_in[1];
  const float* mW1  = (const float*)d_in[2];
  const float* mb1  = (const float*)d_in[3];
  const float* mW2  = (const float*)d_in[4];
  const float* mb2  = (const float*)d_in[5];
  const float* ln1g = (const float*)d_in[6];
  const float* ln1b = (const float*)d_in[7];
  const float* Wqkv = (const float*)d_in[8];
  const float* bqkv = (const float*)d_in[9];
  const float* Wo   = (const float*)d_in[10];
  const float* bo   = (const float*)d_in[11];
  const float* ln2g = (const float*)d_in[12];
  const float* ln2b = (const float*)d_in[13];
  const float* fW1  = (const float*)d_in[14];
  const float* fb1  = (const float*)d_in[15];
  const float* fW2  = (const float*)d_in[16];
  const float* fb2  = (const float*)d_in[17];
  float* outp = (float*)d_out;
  char* ws = (char*)d_ws;

  // workspace layout (bytes); total ~134.4 MB
  unsigned short* w1b   = (unsigned short*)(ws + 0ull);          // 8 MB
  unsigned short* w2b   = (unsigned short*)(ws + 8388608ull);    // 8 MB
  unsigned short* wqkvb = (unsigned short*)(ws + 16777216ull);   // 6 MB
  unsigned short* wob   = (unsigned short*)(ws + 23068672ull);   // 2 MB
  unsigned short* fw1b  = (unsigned short*)(ws + 25165824ull);   // 8 MB
  unsigned short* fw2b  = (unsigned short*)(ws + 33554432ull);   // 8 MB
  const size_t S = 41943040ull;
  float* aug  = (float*)(ws + S);                                // 16.8 MB
  float* hres = (float*)(ws + S + 16809984ull);                  // 16.8 MB
  char*  BBp  = ws + S + 33619968ull;                            // 50.4 MB shared region
  unsigned short* xb   = (unsigned short*)(BBp);                 // stages 1-2
  unsigned short* h1   = (unsigned short*)(BBp + 4194304ull);    // stages 2-3
  float* memctx        = (float*)(BBp + 20971520ull);            // stages 3-4
  float* qkv           = (float*)(BBp);                          // stages 6-7
  unsigned short* f1   = (unsigned short*)(BBp);                 // stages 10-11
  unsigned short* hln  = (unsigned short*)(ws + S + 84049920ull);// 8.4 MB (hln/ctx/hln2 share)
  unsigned short* ctxb = hln;
  unsigned short* hln2 = hln;

  auto cvt = [&](const float* src, unsigned short* dst, int n) {
    cvt_bf16_k<<<dim3((n / 4 + 255) / 256), dim3(256), 0, stream>>>(src, dst, n);
  };
  cvt(x,    xb,    B_ * T_ * D_);
  cvt(mW1,  w1b,   MH_ * D_);
  cvt(mW2,  w2b,   D_ * MH_);
  cvt(Wqkv, wqkvb, 3 * D_ * D_);
  cvt(Wo,   wob,   D_ * D_);
  cvt(fW1,  fw1b,  FF_ * D_);
  cvt(fW2,  fw2b,  D_ * FF_);

  const int BT = B_ * T_;   // 2048
  const int BL = B_ * L_;   // 4104

  // 1. h1 = relu(x @ mW1^T + mb1), bf16
  gemm_bt_k<1, 1, 0><<<dim3(MH_ / 128, BT / 128), 256, 0, stream>>>(xb, w1b, mb1, nullptr, h1, BT, MH_, D_);
  // 2. memctx = h1 @ mW2^T + mb2, fp32
  gemm_bt_k<0, 0, 0><<<dim3(D_ / 128, BT / 128), 256, 0, stream>>>(h1, w2b, mb2, nullptr, memctx, BT, D_, MH_);
  // 3. aug = concat(pers, memctx, x)
  concat_k<<<dim3((B_ * L_ * D_ / 4 + 255) / 256), 256, 0, stream>>>(x, pmem, memctx, aug);
  // 4. hln = LN1(aug), bf16
  layernorm_k<<<dim3(BL), 256, 0, stream>>>(aug, ln1g, ln1b, hln);
  // 5. qkv = hln @ Wqkv^T + bqkv, fp32
  gemm_bt_k<0, 0, 0><<<dim3(3 * D_ / 128, (BL + 127) / 128), 256, 0, stream>>>(hln, wqkvb, bqkv, nullptr, qkv, BL, 3 * D_, D_);
  // 6. ctx = sliding-window attention, bf16
  attn_k<<<dim3((L_ + 63) / 64, H_, B_), 256, 0, stream>>>(qkv, ctxb);
  // 7. hres = aug + ctx @ Wo^T + bo, fp32
  gemm_bt_k<0, 0, 1><<<dim3(D_ / 128, (BL + 127) / 128), 256, 0, stream>>>(ctxb, wob, bo, aug, hres, BL, D_, D_);
  // 8. hln2 = LN2(hres), bf16
  layernorm_k<<<dim3(BL), 256, 0, stream>>>(hres, ln2g, ln2b, hln2);
  // 9. f1 = gelu(hln2 @ fW1^T + fb1), bf16
  gemm_bt_k<2, 1, 0><<<dim3(FF_ / 128, (BL + 127) / 128), 256, 0, stream>>>(hln2, fw1b, fb1, nullptr, f1, BL, FF_, D_);
  // 10. out = hres + f1 @ fW2^T + fb2, fp32
  gemm_bt_k<0, 0, 1><<<dim3(D_ / 128, (BL + 127) / 128), 256, 0, stream>>>(f1, fw2b, fb2, hres, outp, BL, D_, FF_);
}

// Round 2
// 501.377 us; speedup vs baseline: 1.3806x; 1.3806x over previous
//
#include <hip/hip_runtime.h>
#include <math.h>

#define D_   1024
#define H_   16
#define DH_  64
#define T_   1024
#define B_   2
#define P_   4
#define L_   2052      // P + 2T
#define WIN_ 256
#define MH_  4096
#define FF_  4096

typedef __attribute__((ext_vector_type(8))) short bf16x8;
typedef __attribute__((ext_vector_type(4))) float f32x4;
typedef __attribute__((ext_vector_type(8))) unsigned short ush8;

__device__ __forceinline__ unsigned short f2bf(float f) {
  unsigned int u = __builtin_bit_cast(unsigned int, f);
  u += 0x7fffu + ((u >> 16) & 1u);           // round to nearest even
  return (unsigned short)(u >> 16);
}
__device__ __forceinline__ float bf2f(unsigned short h) {
  unsigned int u = ((unsigned int)h) << 16;
  return __builtin_bit_cast(float, u);
}

// async global -> LDS, 16B per lane. LDS dest must be wave-uniform base; lane i
// lands at base + i*16B. Global src is per-lane.
__device__ __forceinline__ void gl16(const unsigned short* g, unsigned short* l) {
  __builtin_amdgcn_global_load_lds(
      (const __attribute__((address_space(1))) unsigned int*)g,
      (__attribute__((address_space(3))) unsigned int*)l, 16, 0, 0);
}

// ---------------- fp32 -> bf16 conversion ----------------
__global__ void cvt_bf16_k(const float* __restrict__ in, unsigned short* __restrict__ out, int n) {
  int i = blockIdx.x * blockDim.x + threadIdx.x;
  int e = i * 4;
  if (e >= n) return;
  float4 v = *(const float4*)(in + e);
  ushort4 o;
  o.x = f2bf(v.x); o.y = f2bf(v.y); o.z = f2bf(v.z); o.w = f2bf(v.w);
  *(ushort4*)(out + e) = o;
}

// ---------------- concat: [pers | memctx | x] -> aug ----------------
__global__ void concat_k(const float* __restrict__ x, const float* __restrict__ pmem,
                         const float* __restrict__ memctx, float* __restrict__ aug) {
  int i = blockIdx.x * blockDim.x + threadIdx.x;
  if (i >= (B_ * L_ * D_) / 4) return;
  int e = i * 4;
  int d  = e % D_;
  int rl = (e / D_) % L_;
  int b  = e / (D_ * L_);
  const float* src;
  if (rl < P_)            src = pmem   + rl * D_ + d;
  else if (rl < P_ + T_)  src = memctx + ((size_t)(b * T_ + (rl - P_)) * D_ + d);
  else                    src = x      + ((size_t)(b * T_ + (rl - P_ - T_)) * D_ + d);
  *(float4*)(aug + e) = *(const float4*)(src);
}

// ---------------- layernorm (D=1024), bf16 out ----------------
__global__ __launch_bounds__(256)
void layernorm_k(const float* __restrict__ in, const float* __restrict__ g,
                 const float* __restrict__ bb, unsigned short* __restrict__ out) {
  const int row = blockIdx.x;
  const int tid = threadIdx.x;
  const float* xr = in + (size_t)row * D_;
  float4 v = *(const float4*)(xr + tid * 4);
  float s  = v.x + v.y + v.z + v.w;
  float sq = v.x * v.x + v.y * v.y + v.z * v.z + v.w * v.w;
  #pragma unroll
  for (int o = 1; o < 64; o <<= 1) { s += __shfl_xor(s, o); sq += __shfl_xor(sq, o); }
  __shared__ float red[8];
  const int wid = tid >> 6;
  if ((tid & 63) == 0) { red[wid] = s; red[4 + wid] = sq; }
  __syncthreads();
  s  = red[0] + red[1] + red[2] + red[3];
  sq = red[4] + red[5] + red[6] + red[7];
  const float mean = s * (1.0f / D_);
  const float var  = sq * (1.0f / D_) - mean * mean;
  const float inv  = rsqrtf(var + 1e-5f);
  const int c = tid * 4;
  float4 gv = *(const float4*)(g + c);
  float4 bv = *(const float4*)(bb + c);
  unsigned short* dst = out + (size_t)row * D_ + c;
  dst[0] = f2bf((v.x - mean) * inv * gv.x + bv.x);
  dst[1] = f2bf((v.y - mean) * inv * gv.y + bv.y);
  dst[2] = f2bf((v.z - mean) * inv * gv.z + bv.z);
  dst[3] = f2bf((v.w - mean) * inv * gv.w + bv.w);
}

// ---------------- bf16 MFMA GEMM (m97 structure): C = epi(A[M,K] @ W[N,K]^T + bias) ----------
// Linear LDS + global_load_lds width=16. A rows [gm0, gm0+128) MUST be readable
// (buffers padded to multiples of 128 rows). N, K multiples of 128/32.
template<int ACT, int OUTBF, int RESID>
__global__ __launch_bounds__(256)
void gemm_bt_k(const unsigned short* __restrict__ A,
               const unsigned short* __restrict__ W,
               const float* __restrict__ bias,
               const float* __restrict__ resid,
               void* __restrict__ Cv,
               int M, int N, int K) {
  __shared__ unsigned short As[128 * 32];
  __shared__ unsigned short Bs[128 * 32];
  const int tid  = threadIdx.x;
  const int lane = tid & 63;
  const int w    = tid >> 6;
  const int wr   = w >> 1, wc = w & 1;
  const int gm0  = blockIdx.y * 128;
  const int gn0  = blockIdx.x * 128;

  const f32x4 fz = {0.f, 0.f, 0.f, 0.f};
  f32x4 acc[4][4];
  #pragma unroll
  for (int i = 0; i < 4; ++i)
    #pragma unroll
    for (int j = 0; j < 4; ++j) acc[i][j] = fz;

  // staging: wave w, instr h covers rows [h*64 + w*16, +16), lane -> row +lane/4, k (lane&3)*8
  const int srow = lane >> 2;
  const int skc  = (lane & 3) * 8;
  const unsigned short* gA = A + (size_t)(gm0 + w * 16 + srow) * K + skc;
  const unsigned short* gB = W + (size_t)(gn0 + w * 16 + srow) * K + skc;
  unsigned short* lA = &As[(w * 16) * 32];
  unsigned short* lB = &Bs[(w * 16) * 32];
  const size_t rskip = (size_t)64 * K;

  const int fr = lane & 15;
  const int fk = (lane >> 4) * 8;

  for (int k0 = 0; k0 < K; k0 += 32) {
    gl16(gA + k0,         lA);
    gl16(gA + rskip + k0, lA + 64 * 32);
    gl16(gB + k0,         lB);
    gl16(gB + rskip + k0, lB + 64 * 32);
    __syncthreads();
    bf16x8 af[4], bfr[4];
    #pragma unroll
    for (int i = 0; i < 4; ++i) af[i]  = *(const bf16x8*)&As[(wr * 64 + i * 16 + fr) * 32 + fk];
    #pragma unroll
    for (int j = 0; j < 4; ++j) bfr[j] = *(const bf16x8*)&Bs[(wc * 64 + j * 16 + fr) * 32 + fk];
    #pragma unroll
    for (int i = 0; i < 4; ++i)
      #pragma unroll
      for (int j = 0; j < 4; ++j)
        acc[i][j] = __builtin_amdgcn_mfma_f32_16x16x32_bf16(af[i], bfr[j], acc[i][j], 0, 0, 0);
    __syncthreads();
  }

  // epilogue: C/D layout col = lane&15, row = (lane>>4)*4 + reg
  const int rq = (lane >> 4) * 4;
  #pragma unroll
  for (int i = 0; i < 4; ++i) {
    #pragma unroll
    for (int j = 0; j < 4; ++j) {
      const int col = gn0 + wc * 64 + j * 16 + fr;
      const float bcol = bias[col];
      #pragma unroll
      for (int r = 0; r < 4; ++r) {
        const int row = gm0 + wr * 64 + i * 16 + rq + r;
        if (row < M) {
          float v = acc[i][j][r] + bcol;
          if (RESID) v += resid[(size_t)row * N + col];
          if (ACT == 1) v = fmaxf(v, 0.f);
          if (ACT == 2) v = 0.5f * v * (1.0f + erff(v * 0.70710678f));
          if (OUTBF) ((unsigned short*)Cv)[(size_t)row * N + col] = f2bf(v);
          else       ((float*)Cv)[(size_t)row * N + col] = v;
        }
      }
    }
  }
}

// ---------------- MFMA sliding-window causal attention ----------------
// grid (ceil(L/64), H, B), block 256 = 4 waves. Wave w owns queries [qb+w*16, +16).
// K staged [64][72] bf16; V staged transposed Vt[dim][key]; P via per-wave LDS.
__global__ __launch_bounds__(256)
void attn_k(const float* __restrict__ qkv, unsigned short* __restrict__ ctx) {
  __shared__ unsigned short Kb[64][72];
  __shared__ unsigned short Vt[64][72];
  __shared__ unsigned short Ps[4][16][72];
  const int tid  = threadIdx.x;
  const int lane = tid & 63;
  const int w    = tid >> 6;
  const int l15  = lane & 15;
  const int l4   = lane >> 4;
  const int qb   = blockIdx.x * 64;
  const int h    = blockIdx.y;
  const int b    = blockIdx.z;

  // Q fragments (scaled by 1/8, exact power of 2): lane holds Q[qb+w*16+l15][l4*8 + e]
  int qrow = qb + w * 16 + l15;
  if (qrow >= L_) qrow = L_ - 1;               // clamp: garbage rows masked at store
  const float* qp = qkv + ((size_t)(b * L_ + qrow)) * 3072 + h * 64;
  bf16x8 aq0, aq1;
  #pragma unroll
  for (int e = 0; e < 8; ++e) {
    aq0[e] = (short)f2bf(qp[l4 * 8 + e] * 0.125f);
    aq1[e] = (short)f2bf(qp[32 + l4 * 8 + e] * 0.125f);
  }

  const f32x4 fz = {0.f, 0.f, 0.f, 0.f};
  f32x4 acc_o[4];
  #pragma unroll
  for (int j = 0; j < 4; ++j) acc_o[j] = fz;
  float m_[4], ls[4];
  #pragma unroll
  for (int r = 0; r < 4; ++r) { m_[r] = -3.0e38f; ls[r] = 0.f; }

  int k0 = qb - WIN_;
  if (k0 < 0) k0 = 0;

  for (int kb = k0; kb <= qb; kb += 64) {
    // ---- stage K (row-major) and V (transposed) as bf16 ----
    #pragma unroll
    for (int c = tid; c < 1024; c += 256) {
      const int row = c >> 4;
      const int cc  = (c & 15) * 4;
      const int g   = kb + row;
      float4 kv = make_float4(0.f, 0.f, 0.f, 0.f), vv = kv;
      if (g < L_) {
        const float* base = qkv + ((size_t)(b * L_ + g)) * 3072 + h * 64 + cc;
        kv = *(const float4*)(base + 1024);
        vv = *(const float4*)(base + 2048);
      }
      ushort4 k4; k4.x = f2bf(kv.x); k4.y = f2bf(kv.y); k4.z = f2bf(kv.z); k4.w = f2bf(kv.w);
      *(ushort4*)&Kb[row][cc] = k4;
      Vt[cc + 0][row] = f2bf(vv.x);
      Vt[cc + 1][row] = f2bf(vv.y);
      Vt[cc + 2][row] = f2bf(vv.z);
      Vt[cc + 3][row] = f2bf(vv.w);
    }
    __syncthreads();

    // ---- QK^T: S[q = l4*4+r][k = kt*16+l15] ----
    f32x4 s[4];
    #pragma unroll
    for (int kt = 0; kt < 4; ++kt) {
      bf16x8 bk0 = *(const bf16x8*)&Kb[kt * 16 + l15][l4 * 8];
      bf16x8 bk1 = *(const bf16x8*)&Kb[kt * 16 + l15][32 + l4 * 8];
      f32x4 t = __builtin_amdgcn_mfma_f32_16x16x32_bf16(aq0, bk0, fz, 0, 0, 0);
      s[kt]   = __builtin_amdgcn_mfma_f32_16x16x32_bf16(aq1, bk1, t,  0, 0, 0);
    }

    // ---- online softmax (rows r, reduce across 16-lane group) ----
    #pragma unroll
    for (int r = 0; r < 4; ++r) {
      const int qg = qb + w * 16 + l4 * 4 + r;
      float rm = -3.0e38f;
      #pragma unroll
      for (int kt = 0; kt < 4; ++kt) {
        const int kg = kb + kt * 16 + l15;
        const bool ok = (kg <= qg) && (kg + WIN_ > qg);
        rm = fmaxf(rm, ok ? s[kt][r] : -3.0e38f);
      }
      rm = fmaxf(rm, __shfl_xor(rm, 1));
      rm = fmaxf(rm, __shfl_xor(rm, 2));
      rm = fmaxf(rm, __shfl_xor(rm, 4));
      rm = fmaxf(rm, __shfl_xor(rm, 8));
      const float mn = fmaxf(m_[r], rm);
      const float sf = __expf(m_[r] - mn);
      m_[r] = mn;
      float ps = 0.f;
      #pragma unroll
      for (int kt = 0; kt < 4; ++kt) {
        const int kg = kb + kt * 16 + l15;
        const bool ok = (kg <= qg) && (kg + WIN_ > qg);
        const float p = ok ? __expf(s[kt][r] - mn) : 0.f;
        ps += p;
        Ps[w][l4 * 4 + r][kt * 16 + l15] = f2bf(p);
      }
      ps += __shfl_xor(ps, 1);
      ps += __shfl_xor(ps, 2);
      ps += __shfl_xor(ps, 4);
      ps += __shfl_xor(ps, 8);
      ls[r] = ls[r] * sf + ps;
      #pragma unroll
      for (int j = 0; j < 4; ++j) acc_o[j][r] *= sf;
    }

    // ---- PV: O[q][d] += P[q][k] * V[k][d]; A = Ps rows (q), B = Vt rows (d) ----
    #pragma unroll
    for (int ks = 0; ks < 2; ++ks) {
      bf16x8 pa = *(const bf16x8*)&Ps[w][l15][ks * 32 + l4 * 8];
      #pragma unroll
      for (int j = 0; j < 4; ++j) {
        bf16x8 vb = *(const bf16x8*)&Vt[j * 16 + l15][ks * 32 + l4 * 8];
        acc_o[j] = __builtin_amdgcn_mfma_f32_16x16x32_bf16(pa, vb, acc_o[j], 0, 0, 0);
      }
    }
    __syncthreads();
  }

  #pragma unroll
  for (int r = 0; r < 4; ++r) {
    const int qg = qb + w * 16 + l4 * 4 + r;
    if (qg < L_) {
      const float inv = 1.0f / ls[r];
      unsigned short* dst = ctx + ((size_t)(b * L_ + qg)) * 1024 + h * 64 + l15;
      #pragma unroll
      for (int j = 0; j < 4; ++j) dst[j * 16] = f2bf(acc_o[j][r] * inv);
    }
  }
}

// ---------------- launch ----------------
extern "C" void kernel_launch(void* const* d_in, const int* in_sizes, int n_in,
                              void* d_out, int out_size, void* d_ws, size_t ws_size,
                              hipStream_t stream) {
  (void)in_sizes; (void)n_in; (void)out_size; (void)ws_size;
  const float* x    = (const float*)d_in[0];
  const float* pmem = (const float*)d_in[1];
  const float* mW1  = (const float*)d_in[2];
  const float* mb1  = (const float*)d_in[3];
  const float* mW2  = (const float*)d_in[4];
  const float* mb2  = (const float*)d_in[5];
  const float* ln1g = (const float*)d_in[6];
  const float* ln1b = (const float*)d_in[7];
  const float* Wqkv = (const float*)d_in[8];
  const float* bqkv = (const float*)d_in[9];
  const float* Wo   = (const float*)d_in[10];
  const float* bo   = (const float*)d_in[11];
  const float* ln2g = (const float*)d_in[12];
  const float* ln2b = (const float*)d_in[13];
  const float* fW1  = (const float*)d_in[14];
  const float* fb1  = (const float*)d_in[15];
  const float* fW2  = (const float*)d_in[16];
  const float* fb2  = (const float*)d_in[17];
  float* outp = (float*)d_out;
  char* ws = (char*)d_ws;

  // workspace layout (bytes); total ~134.6 MB
  unsigned short* w1b   = (unsigned short*)(ws + 0ull);          // 8 MB
  unsigned short* w2b   = (unsigned short*)(ws + 8388608ull);    // 8 MB
  unsigned short* wqkvb = (unsigned short*)(ws + 16777216ull);   // 6 MB
  unsigned short* wob   = (unsigned short*)(ws + 23068672ull);   // 2 MB
  unsigned short* fw1b  = (unsigned short*)(ws + 25165824ull);   // 8 MB
  unsigned short* fw2b  = (unsigned short*)(ws + 33554432ull);   // 8 MB
  const size_t S = 41943040ull;
  float* aug  = (float*)(ws + S);                                // 4104x1024 f32
  float* hres = (float*)(ws + S + 16809984ull);                  // 4104x1024 f32
  unsigned short* hlnbuf = (unsigned short*)(ws + S + 33619968ull); // 4224x1024 bf16 (padded, shared hln/ctx/hln2)
  char* R = ws + S + 42270720ull;                                // 50.4 MB shared region
  unsigned short* xb   = (unsigned short*)(R);                   // stage 1   (2048x1024)
  unsigned short* h1   = (unsigned short*)(R + 4194304ull);      // stages 1-2 (2048x4096)
  float* memctx        = (float*)(R + 20971520ull);              // stages 2-3 (2048x1024)
  float* qkv           = (float*)(R);                            // stages 5-6 (4104x3072)
  unsigned short* f1   = (unsigned short*)(R);                   // stages 9-10 (4224x4096, padded)
  unsigned short* hln  = hlnbuf;
  unsigned short* ctxb = hlnbuf;
  unsigned short* hln2 = hlnbuf;

  auto cvt = [&](const float* src, unsigned short* dst, int n) {
    cvt_bf16_k<<<dim3((n / 4 + 255) / 256), dim3(256), 0, stream>>>(src, dst, n);
  };
  cvt(x,    xb,    B_ * T_ * D_);
  cvt(mW1,  w1b,   MH_ * D_);
  cvt(mW2,  w2b,   D_ * MH_);
  cvt(Wqkv, wqkvb, 3 * D_ * D_);
  cvt(Wo,   wob,   D_ * D_);
  cvt(fW1,  fw1b,  FF_ * D_);
  cvt(fW2,  fw2b,  D_ * FF_);

  const int BT = B_ * T_;   // 2048
  const int BL = B_ * L_;   // 4104

  // 1. h1 = relu(x @ mW1^T + mb1), bf16
  gemm_bt_k<1, 1, 0><<<dim3(MH_ / 128, BT / 128), 256, 0, stream>>>(xb, w1b, mb1, nullptr, h1, BT, MH_, D_);
  // 2. memctx = h1 @ mW2^T + mb2, fp32
  gemm_bt_k<0, 0, 0><<<dim3(D_ / 128, BT / 128), 256, 0, stream>>>(h1, w2b, mb2, nullptr, memctx, BT, D_, MH_);
  // 3. aug = concat(pers, memctx, x)
  concat_k<<<dim3((B_ * L_ * D_ / 4 + 255) / 256), 256, 0, stream>>>(x, pmem, memctx, aug);
  // 4. hln = LN1(aug), bf16
  layernorm_k<<<dim3(BL), 256, 0, stream>>>(aug, ln1g, ln1b, hln);
  // 5. qkv = hln @ Wqkv^T + bqkv, fp32
  gemm_bt_k<0, 0, 0><<<dim3(3 * D_ / 128, (BL + 127) / 128), 256, 0, stream>>>(hln, wqkvb, bqkv, nullptr, qkv, BL, 3 * D_, D_);
  // 6. ctx = sliding-window attention (MFMA), bf16
  attn_k<<<dim3((L_ + 63) / 64, H_, B_), 256, 0, stream>>>(qkv, ctxb);
  // 7. hres = aug + ctx @ Wo^T + bo, fp32
  gemm_bt_k<0, 0, 1><<<dim3(D_ / 128, (BL + 127) / 128), 256, 0, stream>>>(ctxb, wob, bo, aug, hres, BL, D_, D_);
  // 8. hln2 = LN2(hres), bf16
  layernorm_k<<<dim3(BL), 256, 0, stream>>>(hres, ln2g, ln2b, hln2);
  // 9. f1 = gelu(hln2 @ fW1^T + fb1), bf16
  gemm_bt_k<2, 1, 0><<<dim3(FF_ / 128, (BL + 127) / 128), 256, 0, stream>>>(hln2, fw1b, fb1, nullptr, f1, BL, FF_, D_);
  // 10. out = hres + f1 @ fW2^T + fb2, fp32
  gemm_bt_k<0, 0, 1><<<dim3(D_ / 128, (BL + 127) / 128), 256, 0, stream>>>(f1, fw2b, fb2, hres, outp, BL, D_, FF_);
}

// Round 3
// 437.410 us; speedup vs baseline: 1.5825x; 1.1462x over previous
//
#include <hip/hip_runtime.h>
#include <math.h>

#define D_   1024
#define H_   16
#define DH_  64
#define T_   1024
#define B_   2
#define P_   4
#define L_   2052      // P + 2T
#define WIN_ 256
#define MH_  4096
#define FF_  4096

typedef __attribute__((ext_vector_type(8))) short bf16x8;
typedef __attribute__((ext_vector_type(4))) float f32x4;
typedef __attribute__((ext_vector_type(8))) unsigned short ush8;

__device__ __forceinline__ unsigned short f2bf(float f) {
  unsigned int u = __builtin_bit_cast(unsigned int, f);
  u += 0x7fffu + ((u >> 16) & 1u);           // round to nearest even
  return (unsigned short)(u >> 16);
}
__device__ __forceinline__ float bf2f(unsigned short h) {
  unsigned int u = ((unsigned int)h) << 16;
  return __builtin_bit_cast(float, u);
}

// async global -> LDS, 16B per lane. LDS dest must be wave-uniform base; lane i
// lands at base + i*16B. Global src is per-lane.
__device__ __forceinline__ void gl16(const unsigned short* g, unsigned short* l) {
  __builtin_amdgcn_global_load_lds(
      (const __attribute__((address_space(1))) unsigned int*)g,
      (__attribute__((address_space(3))) unsigned int*)l, 16, 0, 0);
}

// ---------------- fp32 -> bf16 conversion ----------------
__global__ void cvt_bf16_k(const float* __restrict__ in, unsigned short* __restrict__ out, int n) {
  int i = blockIdx.x * blockDim.x + threadIdx.x;
  int e = i * 4;
  if (e >= n) return;
  float4 v = *(const float4*)(in + e);
  ushort4 o;
  o.x = f2bf(v.x); o.y = f2bf(v.y); o.z = f2bf(v.z); o.w = f2bf(v.w);
  *(ushort4*)(out + e) = o;
}

// ---------------- concat: [pers | memctx | x] -> aug ----------------
__global__ void concat_k(const float* __restrict__ x, const float* __restrict__ pmem,
                         const float* __restrict__ memctx, float* __restrict__ aug) {
  int i = blockIdx.x * blockDim.x + threadIdx.x;
  if (i >= (B_ * L_ * D_) / 4) return;
  int e = i * 4;
  int d  = e % D_;
  int rl = (e / D_) % L_;
  int b  = e / (D_ * L_);
  const float* src;
  if (rl < P_)            src = pmem   + rl * D_ + d;
  else if (rl < P_ + T_)  src = memctx + ((size_t)(b * T_ + (rl - P_)) * D_ + d);
  else                    src = x      + ((size_t)(b * T_ + (rl - P_ - T_)) * D_ + d);
  *(float4*)(aug + e) = *(const float4*)(src);
}

// ---------------- layernorm (D=1024), bf16 out ----------------
__global__ __launch_bounds__(256)
void layernorm_k(const float* __restrict__ in, const float* __restrict__ g,
                 const float* __restrict__ bb, unsigned short* __restrict__ out) {
  const int row = blockIdx.x;
  const int tid = threadIdx.x;
  const float* xr = in + (size_t)row * D_;
  float4 v = *(const float4*)(xr + tid * 4);
  float s  = v.x + v.y + v.z + v.w;
  float sq = v.x * v.x + v.y * v.y + v.z * v.z + v.w * v.w;
  #pragma unroll
  for (int o = 1; o < 64; o <<= 1) { s += __shfl_xor(s, o); sq += __shfl_xor(sq, o); }
  __shared__ float red[8];
  const int wid = tid >> 6;
  if ((tid & 63) == 0) { red[wid] = s; red[4 + wid] = sq; }
  __syncthreads();
  s  = red[0] + red[1] + red[2] + red[3];
  sq = red[4] + red[5] + red[6] + red[7];
  const float mean = s * (1.0f / D_);
  const float var  = sq * (1.0f / D_) - mean * mean;
  const float inv  = rsqrtf(var + 1e-5f);
  const int c = tid * 4;
  float4 gv = *(const float4*)(g + c);
  float4 bv = *(const float4*)(bb + c);
  unsigned short* dst = out + (size_t)row * D_ + c;
  dst[0] = f2bf((v.x - mean) * inv * gv.x + bv.x);
  dst[1] = f2bf((v.y - mean) * inv * gv.y + bv.y);
  dst[2] = f2bf((v.z - mean) * inv * gv.z + bv.z);
  dst[3] = f2bf((v.w - mean) * inv * gv.w + bv.w);
}

// ---------------- bf16 MFMA GEMM: C = epi(A[M,K] @ W[N,K]^T + bias) ----------
// Tile BM x BN, per-wave WM x WN 16x16 frags, wave grid NWR x NWC, KS in-block
// K-split groups (each group = NWR*NWC waves, own LDS staging, own K-slice;
// groups summed via LDS reduce). Linear LDS + global_load_lds width=16.
// A rows [gm0, gm0+BM) MUST be readable (pad buffers). N mult of BN, K mult of 32*KS.
template<int ACT, int OUTBF, int RESID, int WM, int WN, int NWR, int NWC, int KS>
__global__ __launch_bounds__(KS * NWR * NWC * 64)
void gemm_bt_k(const unsigned short* __restrict__ A,
               const unsigned short* __restrict__ W,
               const float* __restrict__ bias,
               const float* __restrict__ resid,
               void* __restrict__ Cv,
               int M, int N, int K) {
  constexpr int NW = NWR * NWC;          // waves per group
  constexpr int BM = NWR * WM * 16;
  constexpr int BN = NWC * WN * 16;
  constexpr int STG = KS * (BM + BN) * 32 * 2;          // staging bytes
  constexpr int RED = (KS > 1) ? BM * BN * 4 : 0;       // reduce bytes
  constexpr int SBYTES = STG > RED ? STG : RED;
  __shared__ __align__(16) char smem[SBYTES];
  unsigned short* sA = (unsigned short*)smem;
  unsigned short* sB = sA + KS * BM * 32;

  const int tid  = threadIdx.x;
  const int lane = tid & 63;
  const int wv   = tid >> 6;
  const int grp  = wv / NW;
  const int wg   = wv % NW;
  const int wr   = wg / NWC, wc = wg % NWC;
  const int gm0  = blockIdx.y * BM;
  const int gn0  = blockIdx.x * BN;
  const int KperG = K / KS;

  const f32x4 fz = {0.f, 0.f, 0.f, 0.f};
  f32x4 acc[WM][WN];
  #pragma unroll
  for (int i = 0; i < WM; ++i)
    #pragma unroll
    for (int j = 0; j < WN; ++j) acc[i][j] = fz;

  const int srow = lane >> 2;
  const int skc  = (lane & 3) * 8;
  const unsigned short* gA = A + (size_t)(gm0 + srow) * K + grp * KperG + skc;
  const unsigned short* gB = W + (size_t)(gn0 + srow) * K + grp * KperG + skc;
  unsigned short* lA = sA + grp * BM * 32;
  unsigned short* lB = sB + grp * BN * 32;

  const int fr = lane & 15;
  const int fk = (lane >> 4) * 8;

  for (int k0 = 0; k0 < KperG; k0 += 32) {
    #pragma unroll
    for (int t = 0; t < BM / (NW * 16); ++t) {
      const int rr = wg * 16 + t * NW * 16;
      gl16(gA + (size_t)rr * K + k0, lA + rr * 32);
    }
    #pragma unroll
    for (int t = 0; t < BN / (NW * 16); ++t) {
      const int rr = wg * 16 + t * NW * 16;
      gl16(gB + (size_t)rr * K + k0, lB + rr * 32);
    }
    __syncthreads();
    bf16x8 af[WM], bfr[WN];
    #pragma unroll
    for (int i = 0; i < WM; ++i) af[i]  = *(const bf16x8*)&lA[(wr * WM * 16 + i * 16 + fr) * 32 + fk];
    #pragma unroll
    for (int j = 0; j < WN; ++j) bfr[j] = *(const bf16x8*)&lB[(wc * WN * 16 + j * 16 + fr) * 32 + fk];
    #pragma unroll
    for (int i = 0; i < WM; ++i)
      #pragma unroll
      for (int j = 0; j < WN; ++j)
        acc[i][j] = __builtin_amdgcn_mfma_f32_16x16x32_bf16(af[i], bfr[j], acc[i][j], 0, 0, 0);
    __syncthreads();
  }

  // ---- cross-group K reduction (deterministic, via LDS) ----
  if (KS > 1) {
    f32x4* sR = (f32x4*)smem;
    const int tg = tid & (NW * 64 - 1);
    for (int g = 1; g < KS; ++g) {
      if (grp == g) {
        #pragma unroll
        for (int i = 0; i < WM; ++i)
          #pragma unroll
          for (int j = 0; j < WN; ++j) sR[(tg * WM + i) * WN + j] = acc[i][j];
      }
      __syncthreads();
      if (grp == 0) {
        #pragma unroll
        for (int i = 0; i < WM; ++i)
          #pragma unroll
          for (int j = 0; j < WN; ++j) {
            f32x4 t = sR[(tg * WM + i) * WN + j];
            #pragma unroll
            for (int r = 0; r < 4; ++r) acc[i][j][r] += t[r];
          }
      }
      __syncthreads();
    }
    if (grp != 0) return;
  }

  // epilogue: C/D layout col = lane&15, row = (lane>>4)*4 + reg
  const int rq = (lane >> 4) * 4;
  #pragma unroll
  for (int i = 0; i < WM; ++i) {
    #pragma unroll
    for (int j = 0; j < WN; ++j) {
      const int col = gn0 + wc * WN * 16 + j * 16 + fr;
      const float bcol = bias[col];
      #pragma unroll
      for (int r = 0; r < 4; ++r) {
        const int row = gm0 + wr * WM * 16 + i * 16 + rq + r;
        if (row < M) {
          float v = acc[i][j][r] + bcol;
          if (RESID) v += resid[(size_t)row * N + col];
          if (ACT == 1) v = fmaxf(v, 0.f);
          if (ACT == 2) v = 0.5f * v * (1.0f + erff(v * 0.70710678f));
          if (OUTBF) ((unsigned short*)Cv)[(size_t)row * N + col] = f2bf(v);
          else       ((float*)Cv)[(size_t)row * N + col] = v;
        }
      }
    }
  }
}

// ---------------- MFMA sliding-window causal attention ----------------
// grid (ceil(L/64), H, B), block 256 = 4 waves. Wave w owns queries [qb+w*16, +16).
// K staged [64][72] bf16; V staged transposed Vt[dim][key]; P via per-wave LDS.
__global__ __launch_bounds__(256)
void attn_k(const float* __restrict__ qkv, unsigned short* __restrict__ ctx) {
  __shared__ unsigned short Kb[64][72];
  __shared__ unsigned short Vt[64][72];
  __shared__ unsigned short Ps[4][16][72];
  const int tid  = threadIdx.x;
  const int lane = tid & 63;
  const int w    = tid >> 6;
  const int l15  = lane & 15;
  const int l4   = lane >> 4;
  const int qb   = blockIdx.x * 64;
  const int h    = blockIdx.y;
  const int b    = blockIdx.z;

  // Q fragments (scaled by 1/8, exact power of 2): lane holds Q[qb+w*16+l15][l4*8 + e]
  int qrow = qb + w * 16 + l15;
  if (qrow >= L_) qrow = L_ - 1;               // clamp: garbage rows masked at store
  const float* qp = qkv + ((size_t)(b * L_ + qrow)) * 3072 + h * 64;
  bf16x8 aq0, aq1;
  #pragma unroll
  for (int e = 0; e < 8; ++e) {
    aq0[e] = (short)f2bf(qp[l4 * 8 + e] * 0.125f);
    aq1[e] = (short)f2bf(qp[32 + l4 * 8 + e] * 0.125f);
  }

  const f32x4 fz = {0.f, 0.f, 0.f, 0.f};
  f32x4 acc_o[4];
  #pragma unroll
  for (int j = 0; j < 4; ++j) acc_o[j] = fz;
  float m_[4], ls[4];
  #pragma unroll
  for (int r = 0; r < 4; ++r) { m_[r] = -3.0e38f; ls[r] = 0.f; }

  int k0 = qb - WIN_;
  if (k0 < 0) k0 = 0;

  for (int kb = k0; kb <= qb; kb += 64) {
    // ---- stage K (row-major) and V (transposed) as bf16 ----
    #pragma unroll
    for (int c = tid; c < 1024; c += 256) {
      const int row = c >> 4;
      const int cc  = (c & 15) * 4;
      const int g   = kb + row;
      float4 kv = make_float4(0.f, 0.f, 0.f, 0.f), vv = kv;
      if (g < L_) {
        const float* base = qkv + ((size_t)(b * L_ + g)) * 3072 + h * 64 + cc;
        kv = *(const float4*)(base + 1024);
        vv = *(const float4*)(base + 2048);
      }
      ushort4 k4; k4.x = f2bf(kv.x); k4.y = f2bf(kv.y); k4.z = f2bf(kv.z); k4.w = f2bf(kv.w);
      *(ushort4*)&Kb[row][cc] = k4;
      Vt[cc + 0][row] = f2bf(vv.x);
      Vt[cc + 1][row] = f2bf(vv.y);
      Vt[cc + 2][row] = f2bf(vv.z);
      Vt[cc + 3][row] = f2bf(vv.w);
    }
    __syncthreads();

    // ---- QK^T: S[q = l4*4+r][k = kt*16+l15] ----
    f32x4 s[4];
    #pragma unroll
    for (int kt = 0; kt < 4; ++kt) {
      bf16x8 bk0 = *(const bf16x8*)&Kb[kt * 16 + l15][l4 * 8];
      bf16x8 bk1 = *(const bf16x8*)&Kb[kt * 16 + l15][32 + l4 * 8];
      f32x4 t = __builtin_amdgcn_mfma_f32_16x16x32_bf16(aq0, bk0, fz, 0, 0, 0);
      s[kt]   = __builtin_amdgcn_mfma_f32_16x16x32_bf16(aq1, bk1, t,  0, 0, 0);
    }

    // ---- online softmax (rows r, reduce across 16-lane group) ----
    #pragma unroll
    for (int r = 0; r < 4; ++r) {
      const int qg = qb + w * 16 + l4 * 4 + r;
      float rm = -3.0e38f;
      #pragma unroll
      for (int kt = 0; kt < 4; ++kt) {
        const int kg = kb + kt * 16 + l15;
        const bool ok = (kg <= qg) && (kg + WIN_ > qg);
        rm = fmaxf(rm, ok ? s[kt][r] : -3.0e38f);
      }
      rm = fmaxf(rm, __shfl_xor(rm, 1));
      rm = fmaxf(rm, __shfl_xor(rm, 2));
      rm = fmaxf(rm, __shfl_xor(rm, 4));
      rm = fmaxf(rm, __shfl_xor(rm, 8));
      const float mn = fmaxf(m_[r], rm);
      const float sf = __expf(m_[r] - mn);
      m_[r] = mn;
      float ps = 0.f;
      #pragma unroll
      for (int kt = 0; kt < 4; ++kt) {
        const int kg = kb + kt * 16 + l15;
        const bool ok = (kg <= qg) && (kg + WIN_ > qg);
        const float p = ok ? __expf(s[kt][r] - mn) : 0.f;
        ps += p;
        Ps[w][l4 * 4 + r][kt * 16 + l15] = f2bf(p);
      }
      ps += __shfl_xor(ps, 1);
      ps += __shfl_xor(ps, 2);
      ps += __shfl_xor(ps, 4);
      ps += __shfl_xor(ps, 8);
      ls[r] = ls[r] * sf + ps;
      #pragma unroll
      for (int j = 0; j < 4; ++j) acc_o[j][r] *= sf;
    }

    // ---- PV: O[q][d] += P[q][k] * V[k][d]; A = Ps rows (q), B = Vt rows (d) ----
    #pragma unroll
    for (int ks = 0; ks < 2; ++ks) {
      bf16x8 pa = *(const bf16x8*)&Ps[w][l15][ks * 32 + l4 * 8];
      #pragma unroll
      for (int j = 0; j < 4; ++j) {
        bf16x8 vb = *(const bf16x8*)&Vt[j * 16 + l15][ks * 32 + l4 * 8];
        acc_o[j] = __builtin_amdgcn_mfma_f32_16x16x32_bf16(pa, vb, acc_o[j], 0, 0, 0);
      }
    }
    __syncthreads();
  }

  #pragma unroll
  for (int r = 0; r < 4; ++r) {
    const int qg = qb + w * 16 + l4 * 4 + r;
    if (qg < L_) {
      const float inv = 1.0f / ls[r];
      unsigned short* dst = ctx + ((size_t)(b * L_ + qg)) * 1024 + h * 64 + l15;
      #pragma unroll
      for (int j = 0; j < 4; ++j) dst[j * 16] = f2bf(acc_o[j][r] * inv);
    }
  }
}

// ---------------- launch ----------------
extern "C" void kernel_launch(void* const* d_in, const int* in_sizes, int n_in,
                              void* d_out, int out_size, void* d_ws, size_t ws_size,
                              hipStream_t stream) {
  (void)in_sizes; (void)n_in; (void)out_size; (void)ws_size;
  const float* x    = (const float*)d_in[0];
  const float* pmem = (const float*)d_in[1];
  const float* mW1  = (const float*)d_in[2];
  const float* mb1  = (const float*)d_in[3];
  const float* mW2  = (const float*)d_in[4];
  const float* mb2  = (const float*)d_in[5];
  const float* ln1g = (const float*)d_in[6];
  const float* ln1b = (const float*)d_in[7];
  const float* Wqkv = (const float*)d_in[8];
  const float* bqkv = (const float*)d_in[9];
  const float* Wo   = (const float*)d_in[10];
  const float* bo   = (const float*)d_in[11];
  const float* ln2g = (const float*)d_in[12];
  const float* ln2b = (const float*)d_in[13];
  const float* fW1  = (const float*)d_in[14];
  const float* fb1  = (const float*)d_in[15];
  const float* fW2  = (const float*)d_in[16];
  const float* fb2  = (const float*)d_in[17];
  float* outp = (float*)d_out;
  char* ws = (char*)d_ws;

  // workspace layout (bytes); total ~134.6 MB
  unsigned short* w1b   = (unsigned short*)(ws + 0ull);          // 8 MB
  unsigned short* w2b   = (unsigned short*)(ws + 8388608ull);    // 8 MB
  unsigned short* wqkvb = (unsigned short*)(ws + 16777216ull);   // 6 MB
  unsigned short* wob   = (unsigned short*)(ws + 23068672ull);   // 2 MB
  unsigned short* fw1b  = (unsigned short*)(ws + 25165824ull);   // 8 MB
  unsigned short* fw2b  = (unsigned short*)(ws + 33554432ull);   // 8 MB
  const size_t S = 41943040ull;
  float* aug  = (float*)(ws + S);                                // 4104x1024 f32
  float* hres = (float*)(ws + S + 16809984ull);                  // 4104x1024 f32
  unsigned short* hlnbuf = (unsigned short*)(ws + S + 33619968ull); // 4224x1024 bf16 (padded, shared hln/ctx/hln2)
  char* R = ws + S + 42270720ull;                                // 50.4 MB shared region
  unsigned short* xb   = (unsigned short*)(R);                   // stage 1   (2048x1024)
  unsigned short* h1   = (unsigned short*)(R + 4194304ull);      // stages 1-2 (2048x4096)
  float* memctx        = (float*)(R + 20971520ull);              // stages 2-3 (2048x1024)
  float* qkv           = (float*)(R);                            // stages 5-6 (4104x3072)
  unsigned short* f1   = (unsigned short*)(R);                   // stages 9-10 (4224x4096, padded)
  unsigned short* hln  = hlnbuf;
  unsigned short* ctxb = hlnbuf;
  unsigned short* hln2 = hlnbuf;

  auto cvt = [&](const float* src, unsigned short* dst, int n) {
    cvt_bf16_k<<<dim3((n / 4 + 255) / 256), dim3(256), 0, stream>>>(src, dst, n);
  };
  cvt(x,    xb,    B_ * T_ * D_);
  cvt(mW1,  w1b,   MH_ * D_);
  cvt(mW2,  w2b,   D_ * MH_);
  cvt(Wqkv, wqkvb, 3 * D_ * D_);
  cvt(Wo,   wob,   D_ * D_);
  cvt(fW1,  fw1b,  FF_ * D_);
  cvt(fW2,  fw2b,  D_ * FF_);

  const int BT = B_ * T_;   // 2048
  const int BL = B_ * L_;   // 4104

  // 1. h1 = relu(x @ mW1^T + mb1), bf16   [std 128x128]
  gemm_bt_k<1, 1, 0, 4, 4, 2, 2, 1><<<dim3(MH_ / 128, BT / 128), 256, 0, stream>>>(xb, w1b, mb1, nullptr, h1, BT, MH_, D_);
  // 2. memctx = h1 @ mW2^T + mb2, fp32    [skinny 128x64, KS=2, 512 thr]
  gemm_bt_k<0, 0, 0, 2, 4, 4, 1, 2><<<dim3(D_ / 64, BT / 128), 512, 0, stream>>>(h1, w2b, mb2, nullptr, memctx, BT, D_, MH_);
  // 3. aug = concat(pers, memctx, x)
  concat_k<<<dim3((B_ * L_ * D_ / 4 + 255) / 256), 256, 0, stream>>>(x, pmem, memctx, aug);
  // 4. hln = LN1(aug), bf16
  layernorm_k<<<dim3(BL), 256, 0, stream>>>(aug, ln1g, ln1b, hln);
  // 5. qkv = hln @ Wqkv^T + bqkv, fp32    [std 128x128]
  gemm_bt_k<0, 0, 0, 4, 4, 2, 2, 1><<<dim3(3 * D_ / 128, (BL + 127) / 128), 256, 0, stream>>>(hln, wqkvb, bqkv, nullptr, qkv, BL, 3 * D_, D_);
  // 6. ctx = sliding-window attention (MFMA), bf16
  attn_k<<<dim3((L_ + 63) / 64, H_, B_), 256, 0, stream>>>(qkv, ctxb);
  // 7. hres = aug + ctx @ Wo^T + bo, fp32 [128x64, KS=1]
  gemm_bt_k<0, 0, 1, 2, 4, 4, 1, 1><<<dim3(D_ / 64, (BL + 127) / 128), 256, 0, stream>>>(ctxb, wob, bo, aug, hres, BL, D_, D_);
  // 8. hln2 = LN2(hres), bf16
  layernorm_k<<<dim3(BL), 256, 0, stream>>>(hres, ln2g, ln2b, hln2);
  // 9. f1 = gelu(hln2 @ fW1^T + fb1), bf16 [std 128x128]
  gemm_bt_k<2, 1, 0, 4, 4, 2, 2, 1><<<dim3(FF_ / 128, (BL + 127) / 128), 256, 0, stream>>>(hln2, fw1b, fb1, nullptr, f1, BL, FF_, D_);
  // 10. out = hres + f1 @ fW2^T + fb2, fp32 [skinny 128x64, KS=2, 512 thr]
  gemm_bt_k<0, 0, 1, 2, 4, 4, 1, 2><<<dim3(D_ / 64, (BL + 127) / 128), 512, 0, stream>>>(f1, fw2b, fb2, hres, outp, BL, D_, FF_);
}

// Round 4
// 410.998 us; speedup vs baseline: 1.6842x; 1.0643x over previous
//
#include <hip/hip_runtime.h>
#include <math.h>

#define D_   1024
#define H_   16
#define DH_  64
#define T_   1024
#define B_   2
#define P_   4
#define L_   2052      // P + 2T
#define WIN_ 256
#define MH_  4096
#define FF_  4096

typedef __attribute__((ext_vector_type(8))) short bf16x8;
typedef __attribute__((ext_vector_type(4))) float f32x4;
typedef __attribute__((ext_vector_type(8))) unsigned short ush8;

__device__ __forceinline__ unsigned short f2bf(float f) {
  unsigned int u = __builtin_bit_cast(unsigned int, f);
  u += 0x7fffu + ((u >> 16) & 1u);           // round to nearest even
  return (unsigned short)(u >> 16);
}
__device__ __forceinline__ float bf2f(unsigned short h) {
  unsigned int u = ((unsigned int)h) << 16;
  return __builtin_bit_cast(float, u);
}

// async global -> LDS, 16B per lane. LDS dest must be wave-uniform base; lane i
// lands at base + i*16B. Global src is per-lane.
__device__ __forceinline__ void gl16(const unsigned short* g, unsigned short* l) {
  __builtin_amdgcn_global_load_lds(
      (const __attribute__((address_space(1))) unsigned int*)g,
      (__attribute__((address_space(3))) unsigned int*)l, 16, 0, 0);
}

// ---------------- fp32 -> bf16 conversion ----------------
__global__ void cvt_bf16_k(const float* __restrict__ in, unsigned short* __restrict__ out, int n) {
  int i = blockIdx.x * blockDim.x + threadIdx.x;
  int e = i * 4;
  if (e >= n) return;
  float4 v = *(const float4*)(in + e);
  ushort4 o;
  o.x = f2bf(v.x); o.y = f2bf(v.y); o.z = f2bf(v.z); o.w = f2bf(v.w);
  *(ushort4*)(out + e) = o;
}

// ---------------- concat: [pers | memctx | x] -> aug ----------------
__global__ void concat_k(const float* __restrict__ x, const float* __restrict__ pmem,
                         const float* __restrict__ memctx, float* __restrict__ aug) {
  int i = blockIdx.x * blockDim.x + threadIdx.x;
  if (i >= (B_ * L_ * D_) / 4) return;
  int e = i * 4;
  int d  = e % D_;
  int rl = (e / D_) % L_;
  int b  = e / (D_ * L_);
  const float* src;
  if (rl < P_)            src = pmem   + rl * D_ + d;
  else if (rl < P_ + T_)  src = memctx + ((size_t)(b * T_ + (rl - P_)) * D_ + d);
  else                    src = x      + ((size_t)(b * T_ + (rl - P_ - T_)) * D_ + d);
  *(float4*)(aug + e) = *(const float4*)(src);
}

// ---------------- layernorm (D=1024), bf16 out ----------------
__global__ __launch_bounds__(256)
void layernorm_k(const float* __restrict__ in, const float* __restrict__ g,
                 const float* __restrict__ bb, unsigned short* __restrict__ out) {
  const int row = blockIdx.x;
  const int tid = threadIdx.x;
  const float* xr = in + (size_t)row * D_;
  float4 v = *(const float4*)(xr + tid * 4);
  float s  = v.x + v.y + v.z + v.w;
  float sq = v.x * v.x + v.y * v.y + v.z * v.z + v.w * v.w;
  #pragma unroll
  for (int o = 1; o < 64; o <<= 1) { s += __shfl_xor(s, o); sq += __shfl_xor(sq, o); }
  __shared__ float red[8];
  const int wid = tid >> 6;
  if ((tid & 63) == 0) { red[wid] = s; red[4 + wid] = sq; }
  __syncthreads();
  s  = red[0] + red[1] + red[2] + red[3];
  sq = red[4] + red[5] + red[6] + red[7];
  const float mean = s * (1.0f / D_);
  const float var  = sq * (1.0f / D_) - mean * mean;
  const float inv  = rsqrtf(var + 1e-5f);
  const int c = tid * 4;
  float4 gv = *(const float4*)(g + c);
  float4 bv = *(const float4*)(bb + c);
  unsigned short* dst = out + (size_t)row * D_ + c;
  dst[0] = f2bf((v.x - mean) * inv * gv.x + bv.x);
  dst[1] = f2bf((v.y - mean) * inv * gv.y + bv.y);
  dst[2] = f2bf((v.z - mean) * inv * gv.z + bv.z);
  dst[3] = f2bf((v.w - mean) * inv * gv.w + bv.w);
}

// ---------------- bf16 MFMA GEMM: C = epi(A[M,K] @ W[N,K]^T + bias) ----------
// Tile BM x BN, per-wave WM x WN 16x16 frags, wave grid NWR x NWC, KS in-block
// K-split groups (groups summed via LDS reduce). Linear LDS + global_load_lds
// width=16, double-buffered with next-tile prefetch (2-phase): after each
// barrier, issue STAGE(buf^1, t+1) so the DMA is in flight during compute(t);
// the next __syncthreads()'s vmcnt(0) drain then finds it (mostly) done.
// A rows [gm0, gm0+BM) MUST be readable (pad buffers). N mult of BN, K mult of 32*KS.
template<int ACT, int OUTBF, int RESID, int WM, int WN, int NWR, int NWC, int KS>
__global__ __launch_bounds__(KS * NWR * NWC * 64)
void gemm_bt_k(const unsigned short* __restrict__ A,
               const unsigned short* __restrict__ W,
               const float* __restrict__ bias,
               const float* __restrict__ resid,
               void* __restrict__ Cv,
               int M, int N, int K) {
  constexpr int NW = NWR * NWC;          // waves per group
  constexpr int BM = NWR * WM * 16;
  constexpr int BN = NWC * WN * 16;
  constexpr int STG = 2 * KS * (BM + BN) * 32 * 2;      // dbuf staging bytes
  constexpr int RED = (KS > 1) ? BM * BN * 4 : 0;       // reduce bytes
  constexpr int SBYTES = STG > RED ? STG : RED;
  __shared__ __align__(16) char smem[SBYTES];
  unsigned short* sA = (unsigned short*)smem;            // 2*KS buffers of BM*32
  unsigned short* sB = sA + 2 * KS * BM * 32;            // 2*KS buffers of BN*32

  const int tid  = threadIdx.x;
  const int lane = tid & 63;
  const int wv   = tid >> 6;
  const int grp  = wv / NW;
  const int wg   = wv % NW;
  const int wr   = wg / NWC, wc = wg % NWC;
  const int gm0  = blockIdx.y * BM;
  const int gn0  = blockIdx.x * BN;
  const int KperG = K / KS;
  const int NT    = KperG / 32;

  const f32x4 fz = {0.f, 0.f, 0.f, 0.f};
  f32x4 acc[WM][WN];
  #pragma unroll
  for (int i = 0; i < WM; ++i)
    #pragma unroll
    for (int j = 0; j < WN; ++j) acc[i][j] = fz;

  const int srow = lane >> 2;
  const int skc  = (lane & 3) * 8;
  const unsigned short* gA = A + (size_t)(gm0 + srow) * K + grp * KperG + skc;
  const unsigned short* gB = W + (size_t)(gn0 + srow) * K + grp * KperG + skc;

  const int fr = lane & 15;
  const int fk = (lane >> 4) * 8;

  auto stage = [&](int d, int k0) {
    unsigned short* dA = sA + (d * KS + grp) * BM * 32;
    unsigned short* dB = sB + (d * KS + grp) * BN * 32;
    #pragma unroll
    for (int t = 0; t < BM / (NW * 16); ++t) {
      const int rr = wg * 16 + t * NW * 16;
      gl16(gA + (size_t)rr * K + k0, dA + rr * 32);
    }
    #pragma unroll
    for (int t = 0; t < BN / (NW * 16); ++t) {
      const int rr = wg * 16 + t * NW * 16;
      gl16(gB + (size_t)rr * K + k0, dB + rr * 32);
    }
  };

  stage(0, 0);
  for (int kt = 0; kt < NT; ++kt) {
    __syncthreads();                     // vmcnt(0) drain: buf[kt&1] ready
    if (kt + 1 < NT) stage((kt + 1) & 1, (kt + 1) * 32);   // in flight during compute
    const int d = kt & 1;
    const unsigned short* lA = sA + (d * KS + grp) * BM * 32;
    const unsigned short* lB = sB + (d * KS + grp) * BN * 32;
    bf16x8 af[WM], bfr[WN];
    #pragma unroll
    for (int i = 0; i < WM; ++i) af[i]  = *(const bf16x8*)&lA[(wr * WM * 16 + i * 16 + fr) * 32 + fk];
    #pragma unroll
    for (int j = 0; j < WN; ++j) bfr[j] = *(const bf16x8*)&lB[(wc * WN * 16 + j * 16 + fr) * 32 + fk];
    #pragma unroll
    for (int i = 0; i < WM; ++i)
      #pragma unroll
      for (int j = 0; j < WN; ++j)
        acc[i][j] = __builtin_amdgcn_mfma_f32_16x16x32_bf16(af[i], bfr[j], acc[i][j], 0, 0, 0);
  }

  // ---- cross-group K reduction (deterministic, via LDS) ----
  if (KS > 1) {
    __syncthreads();                     // all reads of staging smem done
    f32x4* sR = (f32x4*)smem;
    const int tg = tid & (NW * 64 - 1);
    for (int g = 1; g < KS; ++g) {
      if (grp == g) {
        #pragma unroll
        for (int i = 0; i < WM; ++i)
          #pragma unroll
          for (int j = 0; j < WN; ++j) sR[(tg * WM + i) * WN + j] = acc[i][j];
      }
      __syncthreads();
      if (grp == 0) {
        #pragma unroll
        for (int i = 0; i < WM; ++i)
          #pragma unroll
          for (int j = 0; j < WN; ++j) {
            f32x4 t = sR[(tg * WM + i) * WN + j];
            #pragma unroll
            for (int r = 0; r < 4; ++r) acc[i][j][r] += t[r];
          }
      }
      __syncthreads();
    }
    if (grp != 0) return;
  }

  // epilogue: C/D layout col = lane&15, row = (lane>>4)*4 + reg
  const int rq = (lane >> 4) * 4;
  #pragma unroll
  for (int i = 0; i < WM; ++i) {
    #pragma unroll
    for (int j = 0; j < WN; ++j) {
      const int col = gn0 + wc * WN * 16 + j * 16 + fr;
      const float bcol = bias[col];
      #pragma unroll
      for (int r = 0; r < 4; ++r) {
        const int row = gm0 + wr * WM * 16 + i * 16 + rq + r;
        if (row < M) {
          float v = acc[i][j][r] + bcol;
          if (RESID) v += resid[(size_t)row * N + col];
          if (ACT == 1) v = fmaxf(v, 0.f);
          if (ACT == 2) v = 0.5f * v * (1.0f + erff(v * 0.70710678f));
          if (OUTBF) ((unsigned short*)Cv)[(size_t)row * N + col] = f2bf(v);
          else       ((float*)Cv)[(size_t)row * N + col] = v;
        }
      }
    }
  }
}

// ---------------- MFMA sliding-window causal attention ----------------
// grid (ceil(L/64), H, B), block 256 = 4 waves. Wave w owns queries [qb+w*16, +16).
// K staged [64][72] bf16; V staged transposed Vt[dim][key]; P via per-wave LDS.
__global__ __launch_bounds__(256)
void attn_k(const float* __restrict__ qkv, unsigned short* __restrict__ ctx) {
  __shared__ unsigned short Kb[64][72];
  __shared__ unsigned short Vt[64][72];
  __shared__ unsigned short Ps[4][16][72];
  const int tid  = threadIdx.x;
  const int lane = tid & 63;
  const int w    = tid >> 6;
  const int l15  = lane & 15;
  const int l4   = lane >> 4;
  const int qb   = blockIdx.x * 64;
  const int h    = blockIdx.y;
  const int b    = blockIdx.z;

  // Q fragments (scaled by 1/8, exact power of 2): lane holds Q[qb+w*16+l15][l4*8 + e]
  int qrow = qb + w * 16 + l15;
  if (qrow >= L_) qrow = L_ - 1;               // clamp: garbage rows masked at store
  const float* qp = qkv + ((size_t)(b * L_ + qrow)) * 3072 + h * 64;
  bf16x8 aq0, aq1;
  #pragma unroll
  for (int e = 0; e < 8; ++e) {
    aq0[e] = (short)f2bf(qp[l4 * 8 + e] * 0.125f);
    aq1[e] = (short)f2bf(qp[32 + l4 * 8 + e] * 0.125f);
  }

  const f32x4 fz = {0.f, 0.f, 0.f, 0.f};
  f32x4 acc_o[4];
  #pragma unroll
  for (int j = 0; j < 4; ++j) acc_o[j] = fz;
  float m_[4], ls[4];
  #pragma unroll
  for (int r = 0; r < 4; ++r) { m_[r] = -3.0e38f; ls[r] = 0.f; }

  int k0 = qb - WIN_;
  if (k0 < 0) k0 = 0;

  for (int kb = k0; kb <= qb; kb += 64) {
    // ---- stage K (row-major) and V (transposed) as bf16 ----
    #pragma unroll
    for (int c = tid; c < 1024; c += 256) {
      const int row = c >> 4;
      const int cc  = (c & 15) * 4;
      const int g   = kb + row;
      float4 kv = make_float4(0.f, 0.f, 0.f, 0.f), vv = kv;
      if (g < L_) {
        const float* base = qkv + ((size_t)(b * L_ + g)) * 3072 + h * 64 + cc;
        kv = *(const float4*)(base + 1024);
        vv = *(const float4*)(base + 2048);
      }
      ushort4 k4; k4.x = f2bf(kv.x); k4.y = f2bf(kv.y); k4.z = f2bf(kv.z); k4.w = f2bf(kv.w);
      *(ushort4*)&Kb[row][cc] = k4;
      Vt[cc + 0][row] = f2bf(vv.x);
      Vt[cc + 1][row] = f2bf(vv.y);
      Vt[cc + 2][row] = f2bf(vv.z);
      Vt[cc + 3][row] = f2bf(vv.w);
    }
    __syncthreads();

    // ---- QK^T: S[q = l4*4+r][k = kt*16+l15] ----
    f32x4 s[4];
    #pragma unroll
    for (int kt = 0; kt < 4; ++kt) {
      bf16x8 bk0 = *(const bf16x8*)&Kb[kt * 16 + l15][l4 * 8];
      bf16x8 bk1 = *(const bf16x8*)&Kb[kt * 16 + l15][32 + l4 * 8];
      f32x4 t = __builtin_amdgcn_mfma_f32_16x16x32_bf16(aq0, bk0, fz, 0, 0, 0);
      s[kt]   = __builtin_amdgcn_mfma_f32_16x16x32_bf16(aq1, bk1, t,  0, 0, 0);
    }

    // ---- online softmax (rows r, reduce across 16-lane group) ----
    #pragma unroll
    for (int r = 0; r < 4; ++r) {
      const int qg = qb + w * 16 + l4 * 4 + r;
      float rm = -3.0e38f;
      #pragma unroll
      for (int kt = 0; kt < 4; ++kt) {
        const int kg = kb + kt * 16 + l15;
        const bool ok = (kg <= qg) && (kg + WIN_ > qg);
        rm = fmaxf(rm, ok ? s[kt][r] : -3.0e38f);
      }
      rm = fmaxf(rm, __shfl_xor(rm, 1));
      rm = fmaxf(rm, __shfl_xor(rm, 2));
      rm = fmaxf(rm, __shfl_xor(rm, 4));
      rm = fmaxf(rm, __shfl_xor(rm, 8));
      const float mn = fmaxf(m_[r], rm);
      const float sf = __expf(m_[r] - mn);
      m_[r] = mn;
      float ps = 0.f;
      #pragma unroll
      for (int kt = 0; kt < 4; ++kt) {
        const int kg = kb + kt * 16 + l15;
        const bool ok = (kg <= qg) && (kg + WIN_ > qg);
        const float p = ok ? __expf(s[kt][r] - mn) : 0.f;
        ps += p;
        Ps[w][l4 * 4 + r][kt * 16 + l15] = f2bf(p);
      }
      ps += __shfl_xor(ps, 1);
      ps += __shfl_xor(ps, 2);
      ps += __shfl_xor(ps, 4);
      ps += __shfl_xor(ps, 8);
      ls[r] = ls[r] * sf + ps;
      #pragma unroll
      for (int j = 0; j < 4; ++j) acc_o[j][r] *= sf;
    }

    // ---- PV: O[q][d] += P[q][k] * V[k][d]; A = Ps rows (q), B = Vt rows (d) ----
    #pragma unroll
    for (int ks = 0; ks < 2; ++ks) {
      bf16x8 pa = *(const bf16x8*)&Ps[w][l15][ks * 32 + l4 * 8];
      #pragma unroll
      for (int j = 0; j < 4; ++j) {
        bf16x8 vb = *(const bf16x8*)&Vt[j * 16 + l15][ks * 32 + l4 * 8];
        acc_o[j] = __builtin_amdgcn_mfma_f32_16x16x32_bf16(pa, vb, acc_o[j], 0, 0, 0);
      }
    }
    __syncthreads();
  }

  #pragma unroll
  for (int r = 0; r < 4; ++r) {
    const int qg = qb + w * 16 + l4 * 4 + r;
    if (qg < L_) {
      const float inv = 1.0f / ls[r];
      unsigned short* dst = ctx + ((size_t)(b * L_ + qg)) * 1024 + h * 64 + l15;
      #pragma unroll
      for (int j = 0; j < 4; ++j) dst[j * 16] = f2bf(acc_o[j][r] * inv);
    }
  }
}

// ---------------- launch ----------------
extern "C" void kernel_launch(void* const* d_in, const int* in_sizes, int n_in,
                              void* d_out, int out_size, void* d_ws, size_t ws_size,
                              hipStream_t stream) {
  (void)in_sizes; (void)n_in; (void)out_size; (void)ws_size;
  const float* x    = (const float*)d_in[0];
  const float* pmem = (const float*)d_in[1];
  const float* mW1  = (const float*)d_in[2];
  const float* mb1  = (const float*)d_in[3];
  const float* mW2  = (const float*)d_in[4];
  const float* mb2  = (const float*)d_in[5];
  const float* ln1g = (const float*)d_in[6];
  const float* ln1b = (const float*)d_in[7];
  const float* Wqkv = (const float*)d_in[8];
  const float* bqkv = (const float*)d_in[9];
  const float* Wo   = (const float*)d_in[10];
  const float* bo   = (const float*)d_in[11];
  const float* ln2g = (const float*)d_in[12];
  const float* ln2b = (const float*)d_in[13];
  const float* fW1  = (const float*)d_in[14];
  const float* fb1  = (const float*)d_in[15];
  const float* fW2  = (const float*)d_in[16];
  const float* fb2  = (const float*)d_in[17];
  float* outp = (float*)d_out;
  char* ws = (char*)d_ws;

  // workspace layout (bytes); total ~134.6 MB
  unsigned short* w1b   = (unsigned short*)(ws + 0ull);          // 8 MB
  unsigned short* w2b   = (unsigned short*)(ws + 8388608ull);    // 8 MB
  unsigned short* wqkvb = (unsigned short*)(ws + 16777216ull);   // 6 MB
  unsigned short* wob   = (unsigned short*)(ws + 23068672ull);   // 2 MB
  unsigned short* fw1b  = (unsigned short*)(ws + 25165824ull);   // 8 MB
  unsigned short* fw2b  = (unsigned short*)(ws + 33554432ull);   // 8 MB
  const size_t S = 41943040ull;
  float* aug  = (float*)(ws + S);                                // 4104x1024 f32
  float* hres = (float*)(ws + S + 16809984ull);                  // 4104x1024 f32
  unsigned short* hlnbuf = (unsigned short*)(ws + S + 33619968ull); // 4224x1024 bf16 (padded, shared hln/ctx/hln2)
  char* R = ws + S + 42270720ull;                                // 50.4 MB shared region
  unsigned short* xb   = (unsigned short*)(R);                   // stage 1   (2048x1024)
  unsigned short* h1   = (unsigned short*)(R + 4194304ull);      // stages 1-2 (2048x4096)
  float* memctx        = (float*)(R + 20971520ull);              // stages 2-3 (2048x1024)
  float* qkv           = (float*)(R);                            // stages 5-6 (4104x3072)
  unsigned short* f1   = (unsigned short*)(R);                   // stages 9-10 (4224x4096, padded)
  unsigned short* hln  = hlnbuf;
  unsigned short* ctxb = hlnbuf;
  unsigned short* hln2 = hlnbuf;

  auto cvt = [&](const float* src, unsigned short* dst, int n) {
    cvt_bf16_k<<<dim3((n / 4 + 255) / 256), dim3(256), 0, stream>>>(src, dst, n);
  };
  cvt(x,    xb,    B_ * T_ * D_);
  cvt(mW1,  w1b,   MH_ * D_);
  cvt(mW2,  w2b,   D_ * MH_);
  cvt(Wqkv, wqkvb, 3 * D_ * D_);
  cvt(Wo,   wob,   D_ * D_);
  cvt(fW1,  fw1b,  FF_ * D_);
  cvt(fW2,  fw2b,  D_ * FF_);

  const int BT = B_ * T_;   // 2048
  const int BL = B_ * L_;   // 4104

  // 1. h1 = relu(x @ mW1^T + mb1), bf16   [std 128x128]
  gemm_bt_k<1, 1, 0, 4, 4, 2, 2, 1><<<dim3(MH_ / 128, BT / 128), 256, 0, stream>>>(xb, w1b, mb1, nullptr, h1, BT, MH_, D_);
  // 2. memctx = h1 @ mW2^T + mb2, fp32    [skinny 128x64, KS=2, 512 thr]
  gemm_bt_k<0, 0, 0, 2, 4, 4, 1, 2><<<dim3(D_ / 64, BT / 128), 512, 0, stream>>>(h1, w2b, mb2, nullptr, memctx, BT, D_, MH_);
  // 3. aug = concat(pers, memctx, x)
  concat_k<<<dim3((B_ * L_ * D_ / 4 + 255) / 256), 256, 0, stream>>>(x, pmem, memctx, aug);
  // 4. hln = LN1(aug), bf16
  layernorm_k<<<dim3(BL), 256, 0, stream>>>(aug, ln1g, ln1b, hln);
  // 5. qkv = hln @ Wqkv^T + bqkv, fp32    [std 128x128]
  gemm_bt_k<0, 0, 0, 4, 4, 2, 2, 1><<<dim3(3 * D_ / 128, (BL + 127) / 128), 256, 0, stream>>>(hln, wqkvb, bqkv, nullptr, qkv, BL, 3 * D_, D_);
  // 6. ctx = sliding-window attention (MFMA), bf16
  attn_k<<<dim3((L_ + 63) / 64, H_, B_), 256, 0, stream>>>(qkv, ctxb);
  // 7. hres = aug + ctx @ Wo^T + bo, fp32 [128x64, KS=1]
  gemm_bt_k<0, 0, 1, 2, 4, 4, 1, 1><<<dim3(D_ / 64, (BL + 127) / 128), 256, 0, stream>>>(ctxb, wob, bo, aug, hres, BL, D_, D_);
  // 8. hln2 = LN2(hres), bf16
  layernorm_k<<<dim3(BL), 256, 0, stream>>>(hres, ln2g, ln2b, hln2);
  // 9. f1 = gelu(hln2 @ fW1^T + fb1), bf16 [std 128x128]
  gemm_bt_k<2, 1, 0, 4, 4, 2, 2, 1><<<dim3(FF_ / 128, (BL + 127) / 128), 256, 0, stream>>>(hln2, fw1b, fb1, nullptr, f1, BL, FF_, D_);
  // 10. out = hres + f1 @ fW2^T + fb2, fp32 [skinny 128x64, KS=2, 512 thr]
  gemm_bt_k<0, 0, 1, 2, 4, 4, 1, 2><<<dim3(D_ / 64, (BL + 127) / 128), 512, 0, stream>>>(f1, fw2b, fb2, hres, outp, BL, D_, FF_);
}

// Round 5
// 373.428 us; speedup vs baseline: 1.8537x; 1.1006x over previous
//
#include <hip/hip_runtime.h>
#include <math.h>

#define D_   1024
#define H_   16
#define DH_  64
#define T_   1024
#define B_   2
#define P_   4
#define L_   2052      // P + 2T
#define WIN_ 256
#define MH_  4096
#define FF_  4096

typedef __attribute__((ext_vector_type(8))) short bf16x8;
typedef __attribute__((ext_vector_type(4))) float f32x4;
typedef __attribute__((ext_vector_type(8))) unsigned short ush8;

__device__ __forceinline__ unsigned short f2bf(float f) {
  unsigned int u = __builtin_bit_cast(unsigned int, f);
  u += 0x7fffu + ((u >> 16) & 1u);           // round to nearest even
  return (unsigned short)(u >> 16);
}
__device__ __forceinline__ float bf2f(unsigned short h) {
  unsigned int u = ((unsigned int)h) << 16;
  return __builtin_bit_cast(float, u);
}

// async global -> LDS, 16B per lane. LDS dest must be wave-uniform base; lane i
// lands at base + i*16B. Global src is per-lane.
__device__ __forceinline__ void gl16(const unsigned short* g, unsigned short* l) {
  __builtin_amdgcn_global_load_lds(
      (const __attribute__((address_space(1))) unsigned int*)g,
      (__attribute__((address_space(3))) unsigned int*)l, 16, 0, 0);
}

// ---------------- fp32 -> bf16 conversion ----------------
__global__ void cvt_bf16_k(const float* __restrict__ in, unsigned short* __restrict__ out, int n) {
  int i = blockIdx.x * blockDim.x + threadIdx.x;
  int e = i * 4;
  if (e >= n) return;
  float4 v = *(const float4*)(in + e);
  ushort4 o;
  o.x = f2bf(v.x); o.y = f2bf(v.y); o.z = f2bf(v.z); o.w = f2bf(v.w);
  *(ushort4*)(out + e) = o;
}

// ---- concat + gemm2 split-K reduce: aug = [pers | (p0+p1+mb2) | x] ----
__global__ void concat_k(const float* __restrict__ x, const float* __restrict__ pmem,
                         const float* __restrict__ p0, const float* __restrict__ p1,
                         const float* __restrict__ mb2, float* __restrict__ aug) {
  int i = blockIdx.x * blockDim.x + threadIdx.x;
  if (i >= (B_ * L_ * D_) / 4) return;
  int e = i * 4;
  int d  = e % D_;
  int rl = (e / D_) % L_;
  int b  = e / (D_ * L_);
  float4 v;
  if (rl < P_) {
    v = *(const float4*)(pmem + rl * D_ + d);
  } else if (rl < P_ + T_) {
    size_t idx = (size_t)(b * T_ + (rl - P_)) * D_ + d;
    float4 a0 = *(const float4*)(p0 + idx);
    float4 a1 = *(const float4*)(p1 + idx);
    float4 bb = *(const float4*)(mb2 + d);
    v = make_float4(a0.x + a1.x + bb.x, a0.y + a1.y + bb.y,
                    a0.z + a1.z + bb.z, a0.w + a1.w + bb.w);
  } else {
    v = *(const float4*)(x + (size_t)(b * T_ + (rl - P_ - T_)) * D_ + d);
  }
  *(float4*)(aug + e) = v;
}

// ---- gemm10 split-K reduce: out = p0 + p1 + fb2 + hres ----
__global__ void reduce10_k(const float* __restrict__ p0, const float* __restrict__ p1,
                           const float* __restrict__ hres, const float* __restrict__ fb2,
                           float* __restrict__ out) {
  int i = blockIdx.x * blockDim.x + threadIdx.x;
  if (i >= (B_ * L_ * D_) / 4) return;
  int e = i * 4;
  int d = e % D_;
  float4 a0 = *(const float4*)(p0 + e);
  float4 a1 = *(const float4*)(p1 + e);
  float4 hr = *(const float4*)(hres + e);
  float4 bb = *(const float4*)(fb2 + d);
  float4 v = make_float4(a0.x + a1.x + hr.x + bb.x, a0.y + a1.y + hr.y + bb.y,
                         a0.z + a1.z + hr.z + bb.z, a0.w + a1.w + hr.w + bb.w);
  *(float4*)(out + e) = v;
}

// ---------------- layernorm (D=1024), bf16 out ----------------
__global__ __launch_bounds__(256)
void layernorm_k(const float* __restrict__ in, const float* __restrict__ g,
                 const float* __restrict__ bb, unsigned short* __restrict__ out) {
  const int row = blockIdx.x;
  const int tid = threadIdx.x;
  const float* xr = in + (size_t)row * D_;
  float4 v = *(const float4*)(xr + tid * 4);
  float s  = v.x + v.y + v.z + v.w;
  float sq = v.x * v.x + v.y * v.y + v.z * v.z + v.w * v.w;
  #pragma unroll
  for (int o = 1; o < 64; o <<= 1) { s += __shfl_xor(s, o); sq += __shfl_xor(sq, o); }
  __shared__ float red[8];
  const int wid = tid >> 6;
  if ((tid & 63) == 0) { red[wid] = s; red[4 + wid] = sq; }
  __syncthreads();
  s  = red[0] + red[1] + red[2] + red[3];
  sq = red[4] + red[5] + red[6] + red[7];
  const float mean = s * (1.0f / D_);
  const float var  = sq * (1.0f / D_) - mean * mean;
  const float inv  = rsqrtf(var + 1e-5f);
  const int c = tid * 4;
  float4 gv = *(const float4*)(g + c);
  float4 bv = *(const float4*)(bb + c);
  unsigned short* dst = out + (size_t)row * D_ + c;
  dst[0] = f2bf((v.x - mean) * inv * gv.x + bv.x);
  dst[1] = f2bf((v.y - mean) * inv * gv.y + bv.y);
  dst[2] = f2bf((v.z - mean) * inv * gv.z + bv.z);
  dst[3] = f2bf((v.w - mean) * inv * gv.w + bv.w);
}

// ---------------- bf16 MFMA GEMM: C = epi(A[M,K] @ W[N,K]^T + bias) ----------
// Tile BM x BN, per-wave WM x WN 16x16 frags, wave grid NWR x NWC, KS in-block
// K-split groups (LDS reduce), PART: grid-z K-split writing raw fp32 partials
// at Cv + z*zstride (no bias/resid/act). K = per-z-slice depth; ldK = row
// stride of A/W. Linear LDS + global_load_lds width=16, double-buffered with
// next-tile prefetch. A rows [gm0, gm0+BM) MUST be readable (pad buffers).
template<int ACT, int OUTBF, int RESID, int WM, int WN, int NWR, int NWC, int KS, int PART>
__global__ __launch_bounds__(KS * NWR * NWC * 64)
void gemm_bt_k(const unsigned short* __restrict__ A,
               const unsigned short* __restrict__ W,
               const float* __restrict__ bias,
               const float* __restrict__ resid,
               void* __restrict__ Cv,
               int M, int N, int K, int ldK, long long zstride) {
  constexpr int NW = NWR * NWC;          // waves per group
  constexpr int BM = NWR * WM * 16;
  constexpr int BN = NWC * WN * 16;
  constexpr int STG = 2 * KS * (BM + BN) * 32 * 2;      // dbuf staging bytes
  constexpr int RED = (KS > 1) ? BM * BN * 4 : 0;       // reduce bytes
  constexpr int SBYTES = STG > RED ? STG : RED;
  __shared__ __align__(16) char smem[SBYTES];
  unsigned short* sA = (unsigned short*)smem;            // 2*KS buffers of BM*32
  unsigned short* sB = sA + 2 * KS * BM * 32;            // 2*KS buffers of BN*32

  const int tid  = threadIdx.x;
  const int lane = tid & 63;
  const int wv   = tid >> 6;
  const int grp  = wv / NW;
  const int wg   = wv % NW;
  const int wr   = wg / NWC, wc = wg % NWC;
  const int gm0  = blockIdx.y * BM;
  const int gn0  = blockIdx.x * BN;
  const int KperG = K / KS;
  const int NT    = KperG / 32;
  const int zofs  = PART ? blockIdx.z * K : 0;

  const f32x4 fz = {0.f, 0.f, 0.f, 0.f};
  f32x4 acc[WM][WN];
  #pragma unroll
  for (int i = 0; i < WM; ++i)
    #pragma unroll
    for (int j = 0; j < WN; ++j) acc[i][j] = fz;

  const int srow = lane >> 2;
  const int skc  = (lane & 3) * 8;
  const unsigned short* gA = A + (size_t)(gm0 + srow) * ldK + grp * KperG + zofs + skc;
  const unsigned short* gB = W + (size_t)(gn0 + srow) * ldK + grp * KperG + zofs + skc;

  const int fr = lane & 15;
  const int fk = (lane >> 4) * 8;

  auto stage = [&](int d, int k0) {
    unsigned short* dA = sA + (d * KS + grp) * BM * 32;
    unsigned short* dB = sB + (d * KS + grp) * BN * 32;
    #pragma unroll
    for (int t = 0; t < BM / (NW * 16); ++t) {
      const int rr = wg * 16 + t * NW * 16;
      gl16(gA + (size_t)rr * ldK + k0, dA + rr * 32);
    }
    #pragma unroll
    for (int t = 0; t < BN / (NW * 16); ++t) {
      const int rr = wg * 16 + t * NW * 16;
      gl16(gB + (size_t)rr * ldK + k0, dB + rr * 32);
    }
  };

  stage(0, 0);
  for (int kt = 0; kt < NT; ++kt) {
    __syncthreads();                     // vmcnt(0) drain: buf[kt&1] ready
    if (kt + 1 < NT) stage((kt + 1) & 1, (kt + 1) * 32);   // in flight during compute
    const int d = kt & 1;
    const unsigned short* lA = sA + (d * KS + grp) * BM * 32;
    const unsigned short* lB = sB + (d * KS + grp) * BN * 32;
    bf16x8 af[WM], bfr[WN];
    #pragma unroll
    for (int i = 0; i < WM; ++i) af[i]  = *(const bf16x8*)&lA[(wr * WM * 16 + i * 16 + fr) * 32 + fk];
    #pragma unroll
    for (int j = 0; j < WN; ++j) bfr[j] = *(const bf16x8*)&lB[(wc * WN * 16 + j * 16 + fr) * 32 + fk];
    #pragma unroll
    for (int i = 0; i < WM; ++i)
      #pragma unroll
      for (int j = 0; j < WN; ++j)
        acc[i][j] = __builtin_amdgcn_mfma_f32_16x16x32_bf16(af[i], bfr[j], acc[i][j], 0, 0, 0);
  }

  // ---- cross-group K reduction (deterministic, via LDS) ----
  if (KS > 1) {
    __syncthreads();                     // all reads of staging smem done
    f32x4* sR = (f32x4*)smem;
    const int tg = tid & (NW * 64 - 1);
    for (int g = 1; g < KS; ++g) {
      if (grp == g) {
        #pragma unroll
        for (int i = 0; i < WM; ++i)
          #pragma unroll
          for (int j = 0; j < WN; ++j) sR[(tg * WM + i) * WN + j] = acc[i][j];
      }
      __syncthreads();
      if (grp == 0) {
        #pragma unroll
        for (int i = 0; i < WM; ++i)
          #pragma unroll
          for (int j = 0; j < WN; ++j) {
            f32x4 t = sR[(tg * WM + i) * WN + j];
            #pragma unroll
            for (int r = 0; r < 4; ++r) acc[i][j][r] += t[r];
          }
      }
      __syncthreads();
    }
    if (grp != 0) return;
  }

  // epilogue: C/D layout col = lane&15, row = (lane>>4)*4 + reg
  const int rq = (lane >> 4) * 4;
  if (PART) {
    float* Pout = (float*)Cv + (size_t)blockIdx.z * zstride;
    #pragma unroll
    for (int i = 0; i < WM; ++i) {
      #pragma unroll
      for (int j = 0; j < WN; ++j) {
        const int col = gn0 + wc * WN * 16 + j * 16 + fr;
        #pragma unroll
        for (int r = 0; r < 4; ++r) {
          const int row = gm0 + wr * WM * 16 + i * 16 + rq + r;
          if (row < M) Pout[(size_t)row * N + col] = acc[i][j][r];
        }
      }
    }
    return;
  }
  #pragma unroll
  for (int i = 0; i < WM; ++i) {
    #pragma unroll
    for (int j = 0; j < WN; ++j) {
      const int col = gn0 + wc * WN * 16 + j * 16 + fr;
      const float bcol = bias[col];
      #pragma unroll
      for (int r = 0; r < 4; ++r) {
        const int row = gm0 + wr * WM * 16 + i * 16 + rq + r;
        if (row < M) {
          float v = acc[i][j][r] + bcol;
          if (RESID) v += resid[(size_t)row * N + col];
          if (ACT == 1) v = fmaxf(v, 0.f);
          if (ACT == 2) v = 0.5f * v * (1.0f + erff(v * 0.70710678f));
          if (OUTBF) ((unsigned short*)Cv)[(size_t)row * N + col] = f2bf(v);
          else       ((float*)Cv)[(size_t)row * N + col] = v;
        }
      }
    }
  }
}

// ---------------- MFMA sliding-window causal attention ----------------
// grid (ceil(L/64), H, B), block 256 = 4 waves. Wave w owns queries [qb+w*16, +16).
// K staged [64][72] bf16; V staged transposed Vt[dim][key]; P via per-wave LDS.
__global__ __launch_bounds__(256)
void attn_k(const float* __restrict__ qkv, unsigned short* __restrict__ ctx) {
  __shared__ unsigned short Kb[64][72];
  __shared__ unsigned short Vt[64][72];
  __shared__ unsigned short Ps[4][16][72];
  const int tid  = threadIdx.x;
  const int lane = tid & 63;
  const int w    = tid >> 6;
  const int l15  = lane & 15;
  const int l4   = lane >> 4;
  const int qb   = blockIdx.x * 64;
  const int h    = blockIdx.y;
  const int b    = blockIdx.z;

  // Q fragments (scaled by 1/8, exact power of 2): lane holds Q[qb+w*16+l15][l4*8 + e]
  int qrow = qb + w * 16 + l15;
  if (qrow >= L_) qrow = L_ - 1;               // clamp: garbage rows masked at store
  const float* qp = qkv + ((size_t)(b * L_ + qrow)) * 3072 + h * 64;
  bf16x8 aq0, aq1;
  #pragma unroll
  for (int e = 0; e < 8; ++e) {
    aq0[e] = (short)f2bf(qp[l4 * 8 + e] * 0.125f);
    aq1[e] = (short)f2bf(qp[32 + l4 * 8 + e] * 0.125f);
  }

  const f32x4 fz = {0.f, 0.f, 0.f, 0.f};
  f32x4 acc_o[4];
  #pragma unroll
  for (int j = 0; j < 4; ++j) acc_o[j] = fz;
  float m_[4], ls[4];
  #pragma unroll
  for (int r = 0; r < 4; ++r) { m_[r] = -3.0e38f; ls[r] = 0.f; }

  int k0 = qb - WIN_;
  if (k0 < 0) k0 = 0;

  for (int kb = k0; kb <= qb; kb += 64) {
    // ---- stage K (row-major) and V (transposed) as bf16 ----
    #pragma unroll
    for (int c = tid; c < 1024; c += 256) {
      const int row = c >> 4;
      const int cc  = (c & 15) * 4;
      const int g   = kb + row;
      float4 kv = make_float4(0.f, 0.f, 0.f, 0.f), vv = kv;
      if (g < L_) {
        const float* base = qkv + ((size_t)(b * L_ + g)) * 3072 + h * 64 + cc;
        kv = *(const float4*)(base + 1024);
        vv = *(const float4*)(base + 2048);
      }
      ushort4 k4; k4.x = f2bf(kv.x); k4.y = f2bf(kv.y); k4.z = f2bf(kv.z); k4.w = f2bf(kv.w);
      *(ushort4*)&Kb[row][cc] = k4;
      Vt[cc + 0][row] = f2bf(vv.x);
      Vt[cc + 1][row] = f2bf(vv.y);
      Vt[cc + 2][row] = f2bf(vv.z);
      Vt[cc + 3][row] = f2bf(vv.w);
    }
    __syncthreads();

    // ---- QK^T: S[q = l4*4+r][k = kt*16+l15] ----
    f32x4 s[4];
    #pragma unroll
    for (int kt = 0; kt < 4; ++kt) {
      bf16x8 bk0 = *(const bf16x8*)&Kb[kt * 16 + l15][l4 * 8];
      bf16x8 bk1 = *(const bf16x8*)&Kb[kt * 16 + l15][32 + l4 * 8];
      f32x4 t = __builtin_amdgcn_mfma_f32_16x16x32_bf16(aq0, bk0, fz, 0, 0, 0);
      s[kt]   = __builtin_amdgcn_mfma_f32_16x16x32_bf16(aq1, bk1, t,  0, 0, 0);
    }

    // ---- online softmax (rows r, reduce across 16-lane group) ----
    #pragma unroll
    for (int r = 0; r < 4; ++r) {
      const int qg = qb + w * 16 + l4 * 4 + r;
      float rm = -3.0e38f;
      #pragma unroll
      for (int kt = 0; kt < 4; ++kt) {
        const int kg = kb + kt * 16 + l15;
        const bool ok = (kg <= qg) && (kg + WIN_ > qg);
        rm = fmaxf(rm, ok ? s[kt][r] : -3.0e38f);
      }
      rm = fmaxf(rm, __shfl_xor(rm, 1));
      rm = fmaxf(rm, __shfl_xor(rm, 2));
      rm = fmaxf(rm, __shfl_xor(rm, 4));
      rm = fmaxf(rm, __shfl_xor(rm, 8));
      const float mn = fmaxf(m_[r], rm);
      const float sf = __expf(m_[r] - mn);
      m_[r] = mn;
      float ps = 0.f;
      #pragma unroll
      for (int kt = 0; kt < 4; ++kt) {
        const int kg = kb + kt * 16 + l15;
        const bool ok = (kg <= qg) && (kg + WIN_ > qg);
        const float p = ok ? __expf(s[kt][r] - mn) : 0.f;
        ps += p;
        Ps[w][l4 * 4 + r][kt * 16 + l15] = f2bf(p);
      }
      ps += __shfl_xor(ps, 1);
      ps += __shfl_xor(ps, 2);
      ps += __shfl_xor(ps, 4);
      ps += __shfl_xor(ps, 8);
      ls[r] = ls[r] * sf + ps;
      #pragma unroll
      for (int j = 0; j < 4; ++j) acc_o[j][r] *= sf;
    }

    // ---- PV: O[q][d] += P[q][k] * V[k][d]; A = Ps rows (q), B = Vt rows (d) ----
    #pragma unroll
    for (int ks = 0; ks < 2; ++ks) {
      bf16x8 pa = *(const bf16x8*)&Ps[w][l15][ks * 32 + l4 * 8];
      #pragma unroll
      for (int j = 0; j < 4; ++j) {
        bf16x8 vb = *(const bf16x8*)&Vt[j * 16 + l15][ks * 32 + l4 * 8];
        acc_o[j] = __builtin_amdgcn_mfma_f32_16x16x32_bf16(pa, vb, acc_o[j], 0, 0, 0);
      }
    }
    __syncthreads();
  }

  #pragma unroll
  for (int r = 0; r < 4; ++r) {
    const int qg = qb + w * 16 + l4 * 4 + r;
    if (qg < L_) {
      const float inv = 1.0f / ls[r];
      unsigned short* dst = ctx + ((size_t)(b * L_ + qg)) * 1024 + h * 64 + l15;
      #pragma unroll
      for (int j = 0; j < 4; ++j) dst[j * 16] = f2bf(acc_o[j][r] * inv);
    }
  }
}

// ---------------- launch ----------------
extern "C" void kernel_launch(void* const* d_in, const int* in_sizes, int n_in,
                              void* d_out, int out_size, void* d_ws, size_t ws_size,
                              hipStream_t stream) {
  (void)in_sizes; (void)n_in; (void)out_size; (void)ws_size;
  const float* x    = (const float*)d_in[0];
  const float* pmem = (const float*)d_in[1];
  const float* mW1  = (const float*)d_in[2];
  const float* mb1  = (const float*)d_in[3];
  const float* mW2  = (const float*)d_in[4];
  const float* mb2  = (const float*)d_in[5];
  const float* ln1g = (const float*)d_in[6];
  const float* ln1b = (const float*)d_in[7];
  const float* Wqkv = (const float*)d_in[8];
  const float* bqkv = (const float*)d_in[9];
  const float* Wo   = (const float*)d_in[10];
  const float* bo   = (const float*)d_in[11];
  const float* ln2g = (const float*)d_in[12];
  const float* ln2b = (const float*)d_in[13];
  const float* fW1  = (const float*)d_in[14];
  const float* fb1  = (const float*)d_in[15];
  const float* fW2  = (const float*)d_in[16];
  const float* fb2  = (const float*)d_in[17];
  float* outp = (float*)d_out;
  char* ws = (char*)d_ws;

  // workspace layout (bytes); total ~134.6 MB
  unsigned short* w1b   = (unsigned short*)(ws + 0ull);          // 8 MB
  unsigned short* w2b   = (unsigned short*)(ws + 8388608ull);    // 8 MB
  unsigned short* wqkvb = (unsigned short*)(ws + 16777216ull);   // 6 MB
  unsigned short* wob   = (unsigned short*)(ws + 23068672ull);   // 2 MB
  unsigned short* fw1b  = (unsigned short*)(ws + 25165824ull);   // 8 MB
  unsigned short* fw2b  = (unsigned short*)(ws + 33554432ull);   // 8 MB
  const size_t S = 41943040ull;
  float* aug  = (float*)(ws + S);                                // 4104x1024 f32
  float* hres = (float*)(ws + S + 16809984ull);                  // 4104x1024 f32
  unsigned short* hlnbuf = (unsigned short*)(ws + S + 33619968ull); // 4224x1024 bf16 (shared hln/ctx/hln2)
  char* R = ws + S + 42270720ull;                                // 50.4 MB shared region
  unsigned short* xb   = (unsigned short*)(R);                   // stage 1   (2048x1024)
  unsigned short* h1   = (unsigned short*)(R + 4194304ull);      // stages 1-2 (2048x4096)
  float* qkv           = (float*)(R);                            // stages 5-6 (4104x3072)
  unsigned short* f1   = (unsigned short*)(R + 15826944ull);     // stages 9-10 (4224x4096, padded, at R tail)
  unsigned short* hln  = hlnbuf;
  unsigned short* ctxb = hlnbuf;
  unsigned short* hln2 = hlnbuf;
  // gemm2 split-K partials: live in (not-yet-written) hres region, contiguous
  float* g2p = hres;                        // 2 x (2048x1024) f32 = 16.8 MB
  // gemm10 split-K partials: p0 in dead aug, p1 in dead hlnbuf + R head
  float* g10p = aug;                        // p0 @ aug
  const long long Z10 = 8404992LL;          // (33619968 bytes)/4: p1 @ hlnbuf base

  auto cvt = [&](const float* src, unsigned short* dst, int n) {
    cvt_bf16_k<<<dim3((n / 4 + 255) / 256), dim3(256), 0, stream>>>(src, dst, n);
  };
  cvt(x,    xb,    B_ * T_ * D_);
  cvt(mW1,  w1b,   MH_ * D_);
  cvt(mW2,  w2b,   D_ * MH_);
  cvt(Wqkv, wqkvb, 3 * D_ * D_);
  cvt(Wo,   wob,   D_ * D_);
  cvt(fW1,  fw1b,  FF_ * D_);
  cvt(fW2,  fw2b,  D_ * FF_);

  const int BT = B_ * T_;   // 2048
  const int BL = B_ * L_;   // 4104
  const int NE4 = B_ * L_ * D_ / 4;

  // 1. h1 = relu(x @ mW1^T + mb1), bf16   [std 128x128]
  gemm_bt_k<1, 1, 0, 4, 4, 2, 2, 1, 0><<<dim3(MH_ / 128, BT / 128), 256, 0, stream>>>(xb, w1b, mb1, nullptr, h1, BT, MH_, D_, D_, 0);
  // 2. split-K pass1: g2p[z] = h1 @ mW2^T (K-halves), raw fp32
  gemm_bt_k<0, 0, 0, 4, 4, 2, 2, 1, 1><<<dim3(D_ / 128, BT / 128, 2), 256, 0, stream>>>(h1, w2b, nullptr, nullptr, g2p, BT, D_, MH_ / 2, MH_, (long long)BT * D_);
  // 3. aug = concat(pers, p0+p1+mb2, x)
  concat_k<<<dim3((NE4 + 255) / 256), 256, 0, stream>>>(x, pmem, g2p, g2p + (size_t)BT * D_, mb2, aug);
  // 4. hln = LN1(aug), bf16
  layernorm_k<<<dim3(BL), 256, 0, stream>>>(aug, ln1g, ln1b, hln);
  // 5. qkv = hln @ Wqkv^T + bqkv, fp32    [std 128x128]
  gemm_bt_k<0, 0, 0, 4, 4, 2, 2, 1, 0><<<dim3(3 * D_ / 128, (BL + 127) / 128), 256, 0, stream>>>(hln, wqkvb, bqkv, nullptr, qkv, BL, 3 * D_, D_, D_, 0);
  // 6. ctx = sliding-window attention (MFMA), bf16
  attn_k<<<dim3((L_ + 63) / 64, H_, B_), 256, 0, stream>>>(qkv, ctxb);
  // 7. hres = aug + ctx @ Wo^T + bo, fp32 [128x64, KS=1]
  gemm_bt_k<0, 0, 1, 2, 4, 4, 1, 1, 0><<<dim3(D_ / 64, (BL + 127) / 128), 256, 0, stream>>>(ctxb, wob, bo, aug, hres, BL, D_, D_, D_, 0);
  // 8. hln2 = LN2(hres), bf16
  layernorm_k<<<dim3(BL), 256, 0, stream>>>(hres, ln2g, ln2b, hln2);
  // 9. f1 = gelu(hln2 @ fW1^T + fb1), bf16 [std 128x128]
  gemm_bt_k<2, 1, 0, 4, 4, 2, 2, 1, 0><<<dim3(FF_ / 128, (BL + 127) / 128), 256, 0, stream>>>(hln2, fw1b, fb1, nullptr, f1, BL, FF_, D_, D_, 0);
  // 10a. split-K pass1: g10p[z] = f1 @ fW2^T (K-halves), raw fp32
  gemm_bt_k<0, 0, 0, 4, 4, 2, 2, 1, 1><<<dim3(D_ / 128, (BL + 127) / 128, 2), 256, 0, stream>>>(f1, fw2b, nullptr, nullptr, g10p, BL, D_, FF_ / 2, FF_, Z10);
  // 10b. out = p0 + p1 + fb2 + hres
  reduce10_k<<<dim3((NE4 + 255) / 256), 256, 0, stream>>>(g10p, g10p + Z10, hres, fb2, outp);
}

// Round 6
// 362.641 us; speedup vs baseline: 1.9088x; 1.0297x over previous
//
#include <hip/hip_runtime.h>
#include <math.h>

#define D_   1024
#define H_   16
#define DH_  64
#define T_   1024
#define B_   2
#define P_   4
#define L_   2052      // P + 2T
#define WIN_ 256
#define MH_  4096
#define FF_  4096

typedef __attribute__((ext_vector_type(8))) short bf16x8;
typedef __attribute__((ext_vector_type(4))) float f32x4;
typedef __attribute__((ext_vector_type(8))) unsigned short ush8;

__device__ __forceinline__ unsigned short f2bf(float f) {
  unsigned int u = __builtin_bit_cast(unsigned int, f);
  u += 0x7fffu + ((u >> 16) & 1u);           // round to nearest even
  return (unsigned short)(u >> 16);
}
__device__ __forceinline__ float bf2f(unsigned short h) {
  unsigned int u = ((unsigned int)h) << 16;
  return __builtin_bit_cast(float, u);
}

// async global -> LDS, 16B per lane. LDS dest must be wave-uniform base; lane i
// lands at base + i*16B. Global src is per-lane.
__device__ __forceinline__ void gl16(const unsigned short* g, unsigned short* l) {
  __builtin_amdgcn_global_load_lds(
      (const __attribute__((address_space(1))) unsigned int*)g,
      (__attribute__((address_space(3))) unsigned int*)l, 16, 0, 0);
}

// ---------------- fp32 -> bf16 conversion ----------------
__global__ void cvt_bf16_k(const float* __restrict__ in, unsigned short* __restrict__ out, int n) {
  int i = blockIdx.x * blockDim.x + threadIdx.x;
  int e = i * 4;
  if (e >= n) return;
  float4 v = *(const float4*)(in + e);
  ushort4 o;
  o.x = f2bf(v.x); o.y = f2bf(v.y); o.z = f2bf(v.z); o.w = f2bf(v.w);
  *(ushort4*)(out + e) = o;
}

// ---- concat + gemm2 split-K reduce: aug = [pers | (p0+p1+mb2) | x] ----
__global__ void concat_k(const float* __restrict__ x, const float* __restrict__ pmem,
                         const float* __restrict__ p0, const float* __restrict__ p1,
                         const float* __restrict__ mb2, float* __restrict__ aug) {
  int i = blockIdx.x * blockDim.x + threadIdx.x;
  if (i >= (B_ * L_ * D_) / 4) return;
  int e = i * 4;
  int d  = e % D_;
  int rl = (e / D_) % L_;
  int b  = e / (D_ * L_);
  float4 v;
  if (rl < P_) {
    v = *(const float4*)(pmem + rl * D_ + d);
  } else if (rl < P_ + T_) {
    size_t idx = (size_t)(b * T_ + (rl - P_)) * D_ + d;
    float4 a0 = *(const float4*)(p0 + idx);
    float4 a1 = *(const float4*)(p1 + idx);
    float4 bb = *(const float4*)(mb2 + d);
    v = make_float4(a0.x + a1.x + bb.x, a0.y + a1.y + bb.y,
                    a0.z + a1.z + bb.z, a0.w + a1.w + bb.w);
  } else {
    v = *(const float4*)(x + (size_t)(b * T_ + (rl - P_ - T_)) * D_ + d);
  }
  *(float4*)(aug + e) = v;
}

// ---- gemm10 split-K reduce: out = p0 + p1 + fb2 + hres ----
__global__ void reduce10_k(const float* __restrict__ p0, const float* __restrict__ p1,
                           const float* __restrict__ hres, const float* __restrict__ fb2,
                           float* __restrict__ out) {
  int i = blockIdx.x * blockDim.x + threadIdx.x;
  if (i >= (B_ * L_ * D_) / 4) return;
  int e = i * 4;
  int d = e % D_;
  float4 a0 = *(const float4*)(p0 + e);
  float4 a1 = *(const float4*)(p1 + e);
  float4 hr = *(const float4*)(hres + e);
  float4 bb = *(const float4*)(fb2 + d);
  float4 v = make_float4(a0.x + a1.x + hr.x + bb.x, a0.y + a1.y + hr.y + bb.y,
                         a0.z + a1.z + hr.z + bb.z, a0.w + a1.w + hr.w + bb.w);
  *(float4*)(out + e) = v;
}

// ---------------- layernorm (D=1024), bf16 out ----------------
__global__ __launch_bounds__(256)
void layernorm_k(const float* __restrict__ in, const float* __restrict__ g,
                 const float* __restrict__ bb, unsigned short* __restrict__ out) {
  const int row = blockIdx.x;
  const int tid = threadIdx.x;
  const float* xr = in + (size_t)row * D_;
  float4 v = *(const float4*)(xr + tid * 4);
  float s  = v.x + v.y + v.z + v.w;
  float sq = v.x * v.x + v.y * v.y + v.z * v.z + v.w * v.w;
  #pragma unroll
  for (int o = 1; o < 64; o <<= 1) { s += __shfl_xor(s, o); sq += __shfl_xor(sq, o); }
  __shared__ float red[8];
  const int wid = tid >> 6;
  if ((tid & 63) == 0) { red[wid] = s; red[4 + wid] = sq; }
  __syncthreads();
  s  = red[0] + red[1] + red[2] + red[3];
  sq = red[4] + red[5] + red[6] + red[7];
  const float mean = s * (1.0f / D_);
  const float var  = sq * (1.0f / D_) - mean * mean;
  const float inv  = rsqrtf(var + 1e-5f);
  const int c = tid * 4;
  float4 gv = *(const float4*)(g + c);
  float4 bv = *(const float4*)(bb + c);
  unsigned short* dst = out + (size_t)row * D_ + c;
  dst[0] = f2bf((v.x - mean) * inv * gv.x + bv.x);
  dst[1] = f2bf((v.y - mean) * inv * gv.y + bv.y);
  dst[2] = f2bf((v.z - mean) * inv * gv.z + bv.z);
  dst[3] = f2bf((v.w - mean) * inv * gv.w + bv.w);
}

// ---------------- bf16 MFMA GEMM: C = epi(A[M,K] @ W[N,K]^T + bias) ----------
// Tile BM x BN, per-wave WM x WN 16x16 frags, wave grid NWR x NWC, KS in-block
// K-split groups (LDS reduce), PART: grid-z K-split writing raw fp32 partials.
// Bijective XCD-aware block swizzle (m204) for L2 locality on A/B panels.
// Linear LDS + global_load_lds width=16, double-buffered with next-tile
// prefetch. A rows [gm0, gm0+BM) MUST be readable (pad buffers).
template<int ACT, int OUTBF, int RESID, int WM, int WN, int NWR, int NWC, int KS, int PART>
__global__ __launch_bounds__(KS * NWR * NWC * 64)
void gemm_bt_k(const unsigned short* __restrict__ A,
               const unsigned short* __restrict__ W,
               const float* __restrict__ bias,
               const float* __restrict__ resid,
               void* __restrict__ Cv,
               int M, int N, int K, int ldK, long long zstride) {
  constexpr int NW = NWR * NWC;          // waves per group
  constexpr int BM = NWR * WM * 16;
  constexpr int BN = NWC * WN * 16;
  constexpr int STG = 2 * KS * (BM + BN) * 32 * 2;      // dbuf staging bytes
  constexpr int RED = (KS > 1) ? BM * BN * 4 : 0;       // reduce bytes
  constexpr int SBYTES = STG > RED ? STG : RED;
  __shared__ __align__(16) char smem[SBYTES];
  unsigned short* sA = (unsigned short*)smem;            // 2*KS buffers of BM*32
  unsigned short* sB = sA + 2 * KS * BM * 32;            // 2*KS buffers of BN*32

  const int tid  = threadIdx.x;
  const int lane = tid & 63;
  const int wv   = tid >> 6;
  const int grp  = wv / NW;
  const int wg   = wv % NW;
  const int wr   = wg / NWC, wc = wg % NWC;

  // bijective XCD swizzle (m204): contiguous tile chunk per XCD
  const unsigned int gridX = gridDim.x;
  const unsigned int flat  = blockIdx.y * gridX + blockIdx.x;
  const unsigned int nwg   = gridX * gridDim.y;
  const unsigned int q8 = nwg >> 3, r8 = nwg & 7;
  const unsigned int xcd = flat & 7, sidx = flat >> 3;
  const unsigned int swz = (xcd < r8 ? xcd * (q8 + 1) : r8 * (q8 + 1) + (xcd - r8) * q8) + sidx;
  const int gm0 = (int)(swz / gridX) * BM;
  const int gn0 = (int)(swz % gridX) * BN;

  const int KperG = K / KS;
  const int NT    = KperG / 32;
  const int zofs  = PART ? blockIdx.z * K : 0;

  const f32x4 fz = {0.f, 0.f, 0.f, 0.f};
  f32x4 acc[WM][WN];
  #pragma unroll
  for (int i = 0; i < WM; ++i)
    #pragma unroll
    for (int j = 0; j < WN; ++j) acc[i][j] = fz;

  const int srow = lane >> 2;
  const int skc  = (lane & 3) * 8;
  const unsigned short* gA = A + (size_t)(gm0 + srow) * ldK + grp * KperG + zofs + skc;
  const unsigned short* gB = W + (size_t)(gn0 + srow) * ldK + grp * KperG + zofs + skc;

  const int fr = lane & 15;
  const int fk = (lane >> 4) * 8;

  auto stage = [&](int d, int k0) {
    unsigned short* dA = sA + (d * KS + grp) * BM * 32;
    unsigned short* dB = sB + (d * KS + grp) * BN * 32;
    #pragma unroll
    for (int t = 0; t < BM / (NW * 16); ++t) {
      const int rr = wg * 16 + t * NW * 16;
      gl16(gA + (size_t)rr * ldK + k0, dA + rr * 32);
    }
    #pragma unroll
    for (int t = 0; t < BN / (NW * 16); ++t) {
      const int rr = wg * 16 + t * NW * 16;
      gl16(gB + (size_t)rr * ldK + k0, dB + rr * 32);
    }
  };

  stage(0, 0);
  for (int kt = 0; kt < NT; ++kt) {
    __syncthreads();                     // vmcnt(0) drain: buf[kt&1] ready
    if (kt + 1 < NT) stage((kt + 1) & 1, (kt + 1) * 32);   // in flight during compute
    const int d = kt & 1;
    const unsigned short* lA = sA + (d * KS + grp) * BM * 32;
    const unsigned short* lB = sB + (d * KS + grp) * BN * 32;
    bf16x8 af[WM], bfr[WN];
    #pragma unroll
    for (int i = 0; i < WM; ++i) af[i]  = *(const bf16x8*)&lA[(wr * WM * 16 + i * 16 + fr) * 32 + fk];
    #pragma unroll
    for (int j = 0; j < WN; ++j) bfr[j] = *(const bf16x8*)&lB[(wc * WN * 16 + j * 16 + fr) * 32 + fk];
    #pragma unroll
    for (int i = 0; i < WM; ++i)
      #pragma unroll
      for (int j = 0; j < WN; ++j)
        acc[i][j] = __builtin_amdgcn_mfma_f32_16x16x32_bf16(af[i], bfr[j], acc[i][j], 0, 0, 0);
  }

  // ---- cross-group K reduction (deterministic, via LDS) ----
  if (KS > 1) {
    __syncthreads();                     // all reads of staging smem done
    f32x4* sR = (f32x4*)smem;
    const int tg = tid & (NW * 64 - 1);
    for (int g = 1; g < KS; ++g) {
      if (grp == g) {
        #pragma unroll
        for (int i = 0; i < WM; ++i)
          #pragma unroll
          for (int j = 0; j < WN; ++j) sR[(tg * WM + i) * WN + j] = acc[i][j];
      }
      __syncthreads();
      if (grp == 0) {
        #pragma unroll
        for (int i = 0; i < WM; ++i)
          #pragma unroll
          for (int j = 0; j < WN; ++j) {
            f32x4 t = sR[(tg * WM + i) * WN + j];
            #pragma unroll
            for (int r = 0; r < 4; ++r) acc[i][j][r] += t[r];
          }
      }
      __syncthreads();
    }
    if (grp != 0) return;
  }

  // epilogue: C/D layout col = lane&15, row = (lane>>4)*4 + reg
  const int rq = (lane >> 4) * 4;
  if (PART) {
    float* Pout = (float*)Cv + (size_t)blockIdx.z * zstride;
    #pragma unroll
    for (int i = 0; i < WM; ++i) {
      #pragma unroll
      for (int j = 0; j < WN; ++j) {
        const int col = gn0 + wc * WN * 16 + j * 16 + fr;
        #pragma unroll
        for (int r = 0; r < 4; ++r) {
          const int row = gm0 + wr * WM * 16 + i * 16 + rq + r;
          if (row < M) Pout[(size_t)row * N + col] = acc[i][j][r];
        }
      }
    }
    return;
  }
  #pragma unroll
  for (int i = 0; i < WM; ++i) {
    #pragma unroll
    for (int j = 0; j < WN; ++j) {
      const int col = gn0 + wc * WN * 16 + j * 16 + fr;
      const float bcol = bias[col];
      #pragma unroll
      for (int r = 0; r < 4; ++r) {
        const int row = gm0 + wr * WM * 16 + i * 16 + rq + r;
        if (row < M) {
          float v = acc[i][j][r] + bcol;
          if (RESID) v += resid[(size_t)row * N + col];
          if (ACT == 1) v = fmaxf(v, 0.f);
          if (ACT == 2) {
            // tanh-form GELU: v*(1 - 1/(exp(2t)+1)), t = 0.79788456*(v + 0.044715 v^3)
            float t = 0.7978845608f * v * (1.0f + 0.044715f * v * v);
            float e = __expf(2.0f * t);
            v = v - __fdividef(v, e + 1.0f);
          }
          if (OUTBF) ((unsigned short*)Cv)[(size_t)row * N + col] = f2bf(v);
          else       ((float*)Cv)[(size_t)row * N + col] = v;
        }
      }
    }
  }
}

// ---------------- MFMA sliding-window causal attention (bf16 qkv) ----------------
// grid (ceil(L/64), H, B), block 256 = 4 waves. Wave w owns queries [qb+w*16, +16).
// K staged [64][72] bf16; V staged transposed Vt[dim][key]; P via per-wave LDS.
__global__ __launch_bounds__(256)
void attn_k(const unsigned short* __restrict__ qkv, unsigned short* __restrict__ ctx) {
  __shared__ unsigned short Kb[64][72];
  __shared__ unsigned short Vt[64][72];
  __shared__ unsigned short Ps[4][16][72];
  const int tid  = threadIdx.x;
  const int lane = tid & 63;
  const int w    = tid >> 6;
  const int l15  = lane & 15;
  const int l4   = lane >> 4;
  const int qb   = blockIdx.x * 64;
  const int h    = blockIdx.y;
  const int b    = blockIdx.z;

  // Q fragments (scaled by 1/8, exact power of 2): lane holds Q[qb+w*16+l15][l4*8 + e]
  int qrow = qb + w * 16 + l15;
  if (qrow >= L_) qrow = L_ - 1;               // clamp: garbage rows masked at store
  const unsigned short* qp = qkv + ((size_t)(b * L_ + qrow)) * 3072 + h * 64;
  bf16x8 aq0, aq1;
  #pragma unroll
  for (int e = 0; e < 8; ++e) {
    aq0[e] = (short)f2bf(bf2f(qp[l4 * 8 + e]) * 0.125f);
    aq1[e] = (short)f2bf(bf2f(qp[32 + l4 * 8 + e]) * 0.125f);
  }

  const f32x4 fz = {0.f, 0.f, 0.f, 0.f};
  f32x4 acc_o[4];
  #pragma unroll
  for (int j = 0; j < 4; ++j) acc_o[j] = fz;
  float m_[4], ls[4];
  #pragma unroll
  for (int r = 0; r < 4; ++r) { m_[r] = -3.0e38f; ls[r] = 0.f; }

  int k0 = qb - WIN_;
  if (k0 < 0) k0 = 0;

  for (int kb = k0; kb <= qb; kb += 64) {
    // ---- stage K (row-major) and V (transposed), both bf16 already ----
    #pragma unroll
    for (int c = tid; c < 512; c += 256) {
      const int row = c >> 3;
      const int cc  = (c & 7) * 8;
      const int g   = kb + row;
      ush8 kv8 = {0, 0, 0, 0, 0, 0, 0, 0}, vv8 = kv8;
      if (g < L_) {
        const unsigned short* base = qkv + ((size_t)(b * L_ + g)) * 3072 + h * 64 + cc;
        kv8 = *(const ush8*)(base + 1024);
        vv8 = *(const ush8*)(base + 2048);
      }
      *(ush8*)&Kb[row][cc] = kv8;
      #pragma unroll
      for (int e = 0; e < 8; ++e) Vt[cc + e][row] = vv8[e];
    }
    __syncthreads();

    // ---- QK^T: S[q = l4*4+r][k = kt*16+l15] ----
    f32x4 s[4];
    #pragma unroll
    for (int kt = 0; kt < 4; ++kt) {
      bf16x8 bk0 = *(const bf16x8*)&Kb[kt * 16 + l15][l4 * 8];
      bf16x8 bk1 = *(const bf16x8*)&Kb[kt * 16 + l15][32 + l4 * 8];
      f32x4 t = __builtin_amdgcn_mfma_f32_16x16x32_bf16(aq0, bk0, fz, 0, 0, 0);
      s[kt]   = __builtin_amdgcn_mfma_f32_16x16x32_bf16(aq1, bk1, t,  0, 0, 0);
    }

    // ---- online softmax (rows r, reduce across 16-lane group) ----
    #pragma unroll
    for (int r = 0; r < 4; ++r) {
      const int qg = qb + w * 16 + l4 * 4 + r;
      float rm = -3.0e38f;
      #pragma unroll
      for (int kt = 0; kt < 4; ++kt) {
        const int kg = kb + kt * 16 + l15;
        const bool ok = (kg <= qg) && (kg + WIN_ > qg);
        rm = fmaxf(rm, ok ? s[kt][r] : -3.0e38f);
      }
      rm = fmaxf(rm, __shfl_xor(rm, 1));
      rm = fmaxf(rm, __shfl_xor(rm, 2));
      rm = fmaxf(rm, __shfl_xor(rm, 4));
      rm = fmaxf(rm, __shfl_xor(rm, 8));
      const float mn = fmaxf(m_[r], rm);
      const float sf = __expf(m_[r] - mn);
      m_[r] = mn;
      float ps = 0.f;
      #pragma unroll
      for (int kt = 0; kt < 4; ++kt) {
        const int kg = kb + kt * 16 + l15;
        const bool ok = (kg <= qg) && (kg + WIN_ > qg);
        const float p = ok ? __expf(s[kt][r] - mn) : 0.f;
        ps += p;
        Ps[w][l4 * 4 + r][kt * 16 + l15] = f2bf(p);
      }
      ps += __shfl_xor(ps, 1);
      ps += __shfl_xor(ps, 2);
      ps += __shfl_xor(ps, 4);
      ps += __shfl_xor(ps, 8);
      ls[r] = ls[r] * sf + ps;
      #pragma unroll
      for (int j = 0; j < 4; ++j) acc_o[j][r] *= sf;
    }

    // ---- PV: O[q][d] += P[q][k] * V[k][d]; A = Ps rows (q), B = Vt rows (d) ----
    #pragma unroll
    for (int ks = 0; ks < 2; ++ks) {
      bf16x8 pa = *(const bf16x8*)&Ps[w][l15][ks * 32 + l4 * 8];
      #pragma unroll
      for (int j = 0; j < 4; ++j) {
        bf16x8 vb = *(const bf16x8*)&Vt[j * 16 + l15][ks * 32 + l4 * 8];
        acc_o[j] = __builtin_amdgcn_mfma_f32_16x16x32_bf16(pa, vb, acc_o[j], 0, 0, 0);
      }
    }
    __syncthreads();
  }

  #pragma unroll
  for (int r = 0; r < 4; ++r) {
    const int qg = qb + w * 16 + l4 * 4 + r;
    if (qg < L_) {
      const float inv = 1.0f / ls[r];
      unsigned short* dst = ctx + ((size_t)(b * L_ + qg)) * 1024 + h * 64 + l15;
      #pragma unroll
      for (int j = 0; j < 4; ++j) dst[j * 16] = f2bf(acc_o[j][r] * inv);
    }
  }
}

// ---------------- launch ----------------
extern "C" void kernel_launch(void* const* d_in, const int* in_sizes, int n_in,
                              void* d_out, int out_size, void* d_ws, size_t ws_size,
                              hipStream_t stream) {
  (void)in_sizes; (void)n_in; (void)out_size; (void)ws_size;
  const float* x    = (const float*)d_in[0];
  const float* pmem = (const float*)d_in[1];
  const float* mW1  = (const float*)d_in[2];
  const float* mb1  = (const float*)d_in[3];
  const float* mW2  = (const float*)d_in[4];
  const float* mb2  = (const float*)d_in[5];
  const float* ln1g = (const float*)d_in[6];
  const float* ln1b = (const float*)d_in[7];
  const float* Wqkv = (const float*)d_in[8];
  const float* bqkv = (const float*)d_in[9];
  const float* Wo   = (const float*)d_in[10];
  const float* bo   = (const float*)d_in[11];
  const float* ln2g = (const float*)d_in[12];
  const float* ln2b = (const float*)d_in[13];
  const float* fW1  = (const float*)d_in[14];
  const float* fb1  = (const float*)d_in[15];
  const float* fW2  = (const float*)d_in[16];
  const float* fb2  = (const float*)d_in[17];
  float* outp = (float*)d_out;
  char* ws = (char*)d_ws;

  // workspace layout (bytes); total ~134.6 MB
  unsigned short* w1b   = (unsigned short*)(ws + 0ull);          // 8 MB
  unsigned short* w2b   = (unsigned short*)(ws + 8388608ull);    // 8 MB
  unsigned short* wqkvb = (unsigned short*)(ws + 16777216ull);   // 6 MB
  unsigned short* wob   = (unsigned short*)(ws + 23068672ull);   // 2 MB
  unsigned short* fw1b  = (unsigned short*)(ws + 25165824ull);   // 8 MB
  unsigned short* fw2b  = (unsigned short*)(ws + 33554432ull);   // 8 MB
  const size_t S = 41943040ull;
  float* aug  = (float*)(ws + S);                                // 4104x1024 f32
  float* hres = (float*)(ws + S + 16809984ull);                  // 4104x1024 f32
  unsigned short* hlnbuf = (unsigned short*)(ws + S + 33619968ull); // 4224x1024 bf16 (shared hln/ctx/hln2)
  char* R = ws + S + 42270720ull;                                // 50.4 MB shared region
  unsigned short* xb   = (unsigned short*)(R);                   // stage 1   (2048x1024)
  unsigned short* h1   = (unsigned short*)(R + 4194304ull);      // stages 1-2 (2048x4096)
  unsigned short* qkvb = (unsigned short*)(R);                   // stages 5-6 (4104x3072 bf16 = 25.2 MB)
  unsigned short* f1   = (unsigned short*)(R + 15826944ull);     // stages 9-10 (4224x4096, padded)
  unsigned short* hln  = hlnbuf;
  unsigned short* ctxb = hlnbuf;
  unsigned short* hln2 = hlnbuf;
  // gemm2 split-K partials: live in (not-yet-written) hres region, contiguous
  float* g2p = hres;                        // 2 x (2048x1024) f32 = 16.8 MB
  // gemm10 split-K partials: p0 in dead aug, p1 in dead hlnbuf + R head
  float* g10p = aug;                        // p0 @ aug
  const long long Z10 = 8404992LL;          // (33619968 bytes)/4: p1 @ hlnbuf base

  auto cvt = [&](const float* src, unsigned short* dst, int n) {
    cvt_bf16_k<<<dim3((n / 4 + 255) / 256), dim3(256), 0, stream>>>(src, dst, n);
  };
  cvt(x,    xb,    B_ * T_ * D_);
  cvt(mW1,  w1b,   MH_ * D_);
  cvt(mW2,  w2b,   D_ * MH_);
  cvt(Wqkv, wqkvb, 3 * D_ * D_);
  cvt(Wo,   wob,   D_ * D_);
  cvt(fW1,  fw1b,  FF_ * D_);
  cvt(fW2,  fw2b,  D_ * FF_);

  const int BT = B_ * T_;   // 2048
  const int BL = B_ * L_;   // 4104
  const int NE4 = B_ * L_ * D_ / 4;

  // 1. h1 = relu(x @ mW1^T + mb1), bf16   [std 128x128]
  gemm_bt_k<1, 1, 0, 4, 4, 2, 2, 1, 0><<<dim3(MH_ / 128, BT / 128), 256, 0, stream>>>(xb, w1b, mb1, nullptr, h1, BT, MH_, D_, D_, 0);
  // 2. split-K pass1: g2p[z] = h1 @ mW2^T (K-halves), raw fp32
  gemm_bt_k<0, 0, 0, 4, 4, 2, 2, 1, 1><<<dim3(D_ / 128, BT / 128, 2), 256, 0, stream>>>(h1, w2b, nullptr, nullptr, g2p, BT, D_, MH_ / 2, MH_, (long long)BT * D_);
  // 3. aug = concat(pers, p0+p1+mb2, x)
  concat_k<<<dim3((NE4 + 255) / 256), 256, 0, stream>>>(x, pmem, g2p, g2p + (size_t)BT * D_, mb2, aug);
  // 4. hln = LN1(aug), bf16
  layernorm_k<<<dim3(BL), 256, 0, stream>>>(aug, ln1g, ln1b, hln);
  // 5. qkv = hln @ Wqkv^T + bqkv, bf16    [std 128x128]
  gemm_bt_k<0, 1, 0, 4, 4, 2, 2, 1, 0><<<dim3(3 * D_ / 128, (BL + 127) / 128), 256, 0, stream>>>(hln, wqkvb, bqkv, nullptr, qkvb, BL, 3 * D_, D_, D_, 0);
  // 6. ctx = sliding-window attention (MFMA), bf16
  attn_k<<<dim3((L_ + 63) / 64, H_, B_), 256, 0, stream>>>(qkvb, ctxb);
  // 7. hres = aug + ctx @ Wo^T + bo, fp32 [128x64, KS=1]
  gemm_bt_k<0, 0, 1, 2, 4, 4, 1, 1, 0><<<dim3(D_ / 64, (BL + 127) / 128), 256, 0, stream>>>(ctxb, wob, bo, aug, hres, BL, D_, D_, D_, 0);
  // 8. hln2 = LN2(hres), bf16
  layernorm_k<<<dim3(BL), 256, 0, stream>>>(hres, ln2g, ln2b, hln2);
  // 9. f1 = gelu(hln2 @ fW1^T + fb1), bf16 [std 128x128, fast tanh-GELU]
  gemm_bt_k<2, 1, 0, 4, 4, 2, 2, 1, 0><<<dim3(FF_ / 128, (BL + 127) / 128), 256, 0, stream>>>(hln2, fw1b, fb1, nullptr, f1, BL, FF_, D_, D_, 0);
  // 10a. split-K pass1: g10p[z] = f1 @ fW2^T (K-halves), raw fp32
  gemm_bt_k<0, 0, 0, 4, 4, 2, 2, 1, 1><<<dim3(D_ / 128, (BL + 127) / 128, 2), 256, 0, stream>>>(f1, fw2b, nullptr, nullptr, g10p, BL, D_, FF_ / 2, FF_, Z10);
  // 10b. out = p0 + p1 + fb2 + hres
  reduce10_k<<<dim3((NE4 + 255) / 256), 256, 0, stream>>>(g10p, g10p + Z10, hres, fb2, outp);
}